// Round 12
// baseline (128.331 us; speedup 1.0000x reference)
//
#include <hip/hip_runtime.h>
#include <hip/hip_bf16.h>
#include <cstdint>

#define T_TOK 1024
#define H_DIM 1024
#define I_DIM 512
#define E_NUM 16
#define TOPK  4

typedef __bf16 bf16;
typedef __bf16 bf16x4 __attribute__((ext_vector_type(4)));
typedef __bf16 bf16x8 __attribute__((ext_vector_type(8)));
typedef float  f32x4  __attribute__((ext_vector_type(4)));

#define GLOAD16(g, l)                                                                   \
  __builtin_amdgcn_global_load_lds((const __attribute__((address_space(1))) void*)(g),  \
                                   (__attribute__((address_space(3))) void*)(l), 16, 0, 0)

// pack two floats -> u32 of two bf16 (lo = first)
__device__ __forceinline__ unsigned int pack2(float lo, float hi) {
  bf16 l = (bf16)lo, h = (bf16)hi;
  unsigned short ls, hs;
  __builtin_memcpy(&ls, &l, 2);
  __builtin_memcpy(&hs, &h, 2);
  return (unsigned int)ls | ((unsigned int)hs << 16);
}

// load a bf16x8 fragment from an 8B-aligned (not 16B) LDS address
__device__ __forceinline__ bf16x8 ldfrag(const bf16* p) {
  bf16x4 lo = *(const bf16x4*)p;
  bf16x4 hi = *(const bf16x4*)(p + 4);
  return __builtin_shufflevector(lo, hi, 0, 1, 2, 3, 4, 5, 6, 7);
}

// ================= fused prep: convx + router_score + init =================
// flat grid: [0,512) convx; [512,768) router_score; [768,772) init
__global__ void prep_kernel(const float* __restrict__ x, bf16* __restrict__ xb,
                            const float* __restrict__ gw,
                            int* __restrict__ topk_e, float* __restrict__ topk_w,
                            int* __restrict__ counts, int* __restrict__ tok,
                            float* __restrict__ wt, int* __restrict__ slot) {
  const int b = blockIdx.x, tid = threadIdx.x;
  if (b < 512) {             // ---- convx
    const int i = b * 256 + tid;
    float4 f0 = ((const float4*)x)[i * 2];
    float4 f1 = ((const float4*)x)[i * 2 + 1];
    bf16x8 p;
    p[0]=(bf16)f0.x; p[1]=(bf16)f0.y; p[2]=(bf16)f0.z; p[3]=(bf16)f0.w;
    p[4]=(bf16)f1.x; p[5]=(bf16)f1.y; p[6]=(bf16)f1.z; p[7]=(bf16)f1.w;
    ((bf16x8*)xb)[i] = p;
  } else if (b < 768) {      // ---- router_score
    const int wave = tid >> 6, lane = tid & 63;
    const int t = (b - 512) * 4 + wave;
    const float4* xr = (const float4*)(x + (size_t)t * H_DIM);
    float4 xv[4];
#pragma unroll
    for (int j = 0; j < 4; ++j) xv[j] = xr[lane + 64 * j];
    float p[E_NUM];
#pragma unroll
    for (int e = 0; e < E_NUM; ++e) {
      const float4* gr = (const float4*)(gw + (size_t)e * H_DIM);
      float s = 0.f;
#pragma unroll
      for (int j = 0; j < 4; ++j) {
        float4 g = gr[lane + 64 * j];
        s += xv[j].x * g.x + xv[j].y * g.y + xv[j].z * g.z + xv[j].w * g.w;
      }
      p[e] = s;
    }
#pragma unroll
    for (int off = 32; off > 0; off >>= 1) {
#pragma unroll
      for (int e = 0; e < E_NUM; ++e) p[e] += __shfl_xor(p[e], off);
    }
    float rem[E_NUM];
#pragma unroll
    for (int e = 0; e < E_NUM; ++e) rem[e] = 1.f / (1.f + __expf(-p[e]));
    float vals[TOPK]; int idx[TOPK];
#pragma unroll
    for (int k = 0; k < TOPK; ++k) {
      float m = rem[0]; int mi = 0;
#pragma unroll
      for (int e = 1; e < E_NUM; ++e) {
        if (rem[e] > m) { m = rem[e]; mi = e; }
      }
      vals[k] = m; idx[k] = mi;
#pragma unroll
      for (int e = 0; e < E_NUM; ++e) rem[e] = (e == mi) ? -1e30f : rem[e];
    }
    if (lane == 0) {
      float inv = 1.f / (vals[0] + vals[1] + vals[2] + vals[3]);
      int4 ids; ids.x = idx[0]; ids.y = idx[1]; ids.z = idx[2]; ids.w = idx[3];
      float4 w4; w4.x = vals[0]*inv; w4.y = vals[1]*inv; w4.z = vals[2]*inv; w4.w = vals[3]*inv;
      ((int4*)topk_e)[t] = ids;
      ((float4*)topk_w)[t] = w4;
    }
  } else {                   // ---- init shared-expert list
    const int i = (b - 768) * 256 + tid;
    if (i == 0) counts[E_NUM] = T_TOK;
    tok [E_NUM * T_TOK + i] = i;
    wt  [E_NUM * T_TOK + i] = 1.0f;
    slot[E_NUM * T_TOK + i] = T_TOK * TOPK + i;
  }
}

// ---------------- router phase 2: per-expert list build via ballot prefix ----------------
__global__ void router_build_kernel(const int* __restrict__ topk_e, const float* __restrict__ topk_w,
                                    int* __restrict__ counts, int* __restrict__ tok,
                                    float* __restrict__ wt, int* __restrict__ slot) {
  const int e = blockIdx.x;  // 0..15
  const int tid = threadIdx.x, wave = tid >> 6, lane = tid & 63;
  __shared__ int wsum[4];
  int base = 0;
  for (int r = 0; r < 4; ++r) {
    int t = r * 256 + tid;
    int4 ids = ((const int4*)topk_e)[t];
    int match = -1;
    if (ids.x == e) match = 0;
    if (ids.y == e) match = 1;
    if (ids.z == e) match = 2;
    if (ids.w == e) match = 3;
    unsigned long long bm = __ballot(match >= 0);
    int prefix = __popcll(bm & ((1ull << lane) - 1ull));
    if (lane == 0) wsum[wave] = __popcll(bm);
    __syncthreads();
    int wbase = 0;
#pragma unroll
    for (int wv = 0; wv < 4; ++wv) wbase += (wv < wave) ? wsum[wv] : 0;
    int total = wsum[0] + wsum[1] + wsum[2] + wsum[3];
    if (match >= 0) {
      int pos = base + wbase + prefix;
      tok [e * T_TOK + pos] = t;
      wt  [e * T_TOK + pos] = topk_w[t * 4 + match];
      slot[e * T_TOK + pos] = t * 4 + match;
    }
    base += total;
    __syncthreads();
  }
  if (tid == 0) counts[e] = base;
}

// ---------------- GEMM1: Xb gathered @ Wgu (fp32, transposed in-kernel) -> wt*swiglu -> h ----------------
// BM=64, BN=64(g)+64(u), BK=32, 4 waves (2x2). A via global_load_lds (linear [64][32]);
// W via reg-staging: fp32 global -> cvt-pack -> conflict-free b32 transposed writes,
// padded stride-36 LDS tiles (conflict-free b64 fragment reads). Double-buffered.
__global__ __launch_bounds__(256, 3)
void gemm1_kernel(const bf16* __restrict__ xb, const float* __restrict__ wguF,
                  const float* __restrict__ sguF, const int* __restrict__ counts,
                  const int* __restrict__ tok, const float* __restrict__ wt,
                  const int* __restrict__ slot, bf16* __restrict__ hbuf) {
  const int e   = blockIdx.z;
  const int cnt = counts[e];
  const int rt  = blockIdx.y;
  if (rt * 64 >= cnt) return;
  const int nb = blockIdx.x * 64;  // h col base within I=512
  const float* BF = (e < E_NUM) ? (wguF + (size_t)e * H_DIM * (2 * I_DIM)) : sguF;  // [1024][1024]

  __shared__ __align__(16) bf16 sA[2][64 * 32];   // linear, gload_lds
  __shared__ __align__(16) bf16 sG[2][64 * 36];   // [n][k] stride 36
  __shared__ __align__(16) bf16 sU[2][64 * 36];

  const int tid = threadIdx.x, wave = tid >> 6, lane = tid & 63;
  const int wr = wave >> 1, wc = wave & 1;
  const int fr = lane & 15, kg = lane >> 4;
  const int lr = lane >> 2, lk = (lane & 3) * 8;

  // A staging (gload_lds, per wave 16 rows x 64B)
  int ar = rt * 64 + wave * 16 + lr;
  int arc = ar < cnt ? ar : cnt - 1;
  const bf16* aS = xb + (size_t)tok[e * T_TOK + arc] * H_DIM + lk;
  const int aOff = wave * 512;

  // W staging: half 0 -> gate, 1 -> up. idx in [0,128): kp = k-pair (16), cg = col-group (8)
  const int half = tid >> 7, idx = tid & 127, kp = idx >> 3, cg = idx & 7;
  const float* wS = BF + (size_t)(2 * kp) * (2 * I_DIM) + half * I_DIM + nb + cg * 8;
  // write target element offsets: (cg*8+j)*36 + 2*kp

  f32x4 accg[2][2], accu[2][2];
#pragma unroll
  for (int i = 0; i < 2; ++i)
#pragma unroll
    for (int j = 0; j < 2; ++j) { accg[i][j] = f32x4{0,0,0,0}; accu[i][j] = f32x4{0,0,0,0}; }

  float r0[8], r1[8];

#define WLOAD(k0) do {                                              \
    const float* wp = wS + (size_t)(k0) * (2 * I_DIM);              \
    *(float4*)&r0[0] = *(const float4*)(wp);                        \
    *(float4*)&r0[4] = *(const float4*)(wp + 4);                    \
    *(float4*)&r1[0] = *(const float4*)(wp + 2 * I_DIM);            \
    *(float4*)&r1[4] = *(const float4*)(wp + 2 * I_DIM + 4);        \
  } while (0)

#define WWRITE(bidx) do {                                           \
    bf16* tgt = half ? sU[bidx] : sG[bidx];                         \
_Pragma("unroll")                                                   \
    for (int j = 0; j < 8; ++j)                                     \
      *(unsigned int*)(tgt + (cg * 8 + j) * 36 + 2 * kp) = pack2(r0[j], r1[j]); \
  } while (0)

  // prologue: tile 0
  GLOAD16(aS, sA[0] + aOff);
  WLOAD(0);
  WWRITE(0);
  __syncthreads();

  const int NT = H_DIM / 32;  // 32
  int cur = 0;
  for (int t = 0; t < NT; ++t) {
    if (t + 1 < NT) {
      GLOAD16(aS + (t + 1) * 32, sA[cur ^ 1] + aOff);
      WLOAD((t + 1) * 32);
    }
    const bf16* A = sA[cur];
    const bf16* G = sG[cur];
    const bf16* U = sU[cur];
    bf16x8 a0 = *(const bf16x8*)(A + (wr * 32      + fr) * 32 + kg * 8);
    bf16x8 a1 = *(const bf16x8*)(A + (wr * 32 + 16 + fr) * 32 + kg * 8);
    bf16x8 g0 = ldfrag(G + (wc * 32      + fr) * 36 + kg * 8);
    bf16x8 g1 = ldfrag(G + (wc * 32 + 16 + fr) * 36 + kg * 8);
    bf16x8 u0 = ldfrag(U + (wc * 32      + fr) * 36 + kg * 8);
    bf16x8 u1 = ldfrag(U + (wc * 32 + 16 + fr) * 36 + kg * 8);
    accg[0][0] = __builtin_amdgcn_mfma_f32_16x16x32_bf16(a0, g0, accg[0][0], 0, 0, 0);
    accg[0][1] = __builtin_amdgcn_mfma_f32_16x16x32_bf16(a0, g1, accg[0][1], 0, 0, 0);
    accg[1][0] = __builtin_amdgcn_mfma_f32_16x16x32_bf16(a1, g0, accg[1][0], 0, 0, 0);
    accg[1][1] = __builtin_amdgcn_mfma_f32_16x16x32_bf16(a1, g1, accg[1][1], 0, 0, 0);
    accu[0][0] = __builtin_amdgcn_mfma_f32_16x16x32_bf16(a0, u0, accu[0][0], 0, 0, 0);
    accu[0][1] = __builtin_amdgcn_mfma_f32_16x16x32_bf16(a0, u1, accu[0][1], 0, 0, 0);
    accu[1][0] = __builtin_amdgcn_mfma_f32_16x16x32_bf16(a1, u0, accu[1][0], 0, 0, 0);
    accu[1][1] = __builtin_amdgcn_mfma_f32_16x16x32_bf16(a1, u1, accu[1][1], 0, 0, 0);
    if (t + 1 < NT) WWRITE(cur ^ 1);   // waits W loads here (after MFMAs)
    __syncthreads();
    cur ^= 1;
  }
#undef WLOAD
#undef WWRITE

  // epilogue: h = wt * swiglu, scatter-store
#pragma unroll
  for (int mi = 0; mi < 2; ++mi) {
#pragma unroll
    for (int j = 0; j < 4; ++j) {
      int grow = rt * 64 + wr * 32 + mi * 16 + kg * 4 + j;
      if (grow < cnt) {
        bf16* hr = hbuf + (size_t)slot[e * T_TOK + grow] * I_DIM;
        float w = wt[e * T_TOK + grow];
#pragma unroll
        for (int ni = 0; ni < 2; ++ni) {
          float g = accg[mi][ni][j], u = accu[mi][ni][j];
          float h = w * (g / (1.f + __expf(-g))) * u;
          hr[nb + wc * 32 + ni * 16 + fr] = (bf16)h;
        }
      }
    }
  }
}

// ---------------- GEMM2: h gathered @ Wd (fp32, transposed in-kernel) -> obuf[slot] ----------------
// BM=64, BN=128, BK=32. Same staging scheme.
__global__ __launch_bounds__(256, 3)
void gemm2_kernel(const bf16* __restrict__ hbuf, const float* __restrict__ wdF,
                  const float* __restrict__ sdF, const int* __restrict__ counts,
                  const int* __restrict__ slot, float* __restrict__ obuf) {
  const int e   = blockIdx.z;
  const int cnt = counts[e];
  const int rt  = blockIdx.y;
  if (rt * 64 >= cnt) return;
  const int nb = blockIdx.x * 128;
  const float* BF = (e < E_NUM) ? (wdF + (size_t)e * I_DIM * H_DIM) : sdF;  // [512][1024]

  __shared__ __align__(16) bf16 sA[2][64 * 32];
  __shared__ __align__(16) bf16 sB[2][128 * 36];

  const int tid = threadIdx.x, wave = tid >> 6, lane = tid & 63;
  const int wr = wave >> 1, wc = wave & 1;
  const int fr = lane & 15, kg = lane >> 4;
  const int lr = lane >> 2, lk = (lane & 3) * 8;

  int ar = rt * 64 + wave * 16 + lr;
  int arc = ar < cnt ? ar : cnt - 1;
  const bf16* aS = hbuf + (size_t)slot[e * T_TOK + arc] * I_DIM + lk;
  const int aOff = wave * 512;

  // W staging: kp = tid>>4 (16 pairs), cg = tid&15 (16 col-groups of 8 -> 128 cols)
  const int kp = tid >> 4, cg = tid & 15;
  const float* wS = BF + (size_t)(2 * kp) * H_DIM + nb + cg * 8;

  f32x4 acc[2][4];
#pragma unroll
  for (int i = 0; i < 2; ++i)
#pragma unroll
    for (int j = 0; j < 4; ++j) acc[i][j] = f32x4{0,0,0,0};

  float r0[8], r1[8];

#define WLOAD2(k0) do {                                             \
    const float* wp = wS + (size_t)(k0) * H_DIM;                    \
    *(float4*)&r0[0] = *(const float4*)(wp);                        \
    *(float4*)&r0[4] = *(const float4*)(wp + 4);                    \
    *(float4*)&r1[0] = *(const float4*)(wp + H_DIM);                \
    *(float4*)&r1[4] = *(const float4*)(wp + H_DIM + 4);            \
  } while (0)

#define WWRITE2(bidx) do {                                          \
    bf16* tgt = sB[bidx];                                           \
_Pragma("unroll")                                                   \
    for (int j = 0; j < 8; ++j)                                     \
      *(unsigned int*)(tgt + (cg * 8 + j) * 36 + 2 * kp) = pack2(r0[j], r1[j]); \
  } while (0)

  GLOAD16(aS, sA[0] + aOff);
  WLOAD2(0);
  WWRITE2(0);
  __syncthreads();

  const int NT = I_DIM / 32;  // 16
  int cur = 0;
  for (int t = 0; t < NT; ++t) {
    if (t + 1 < NT) {
      GLOAD16(aS + (t + 1) * 32, sA[cur ^ 1] + aOff);
      WLOAD2((t + 1) * 32);
    }
    const bf16* A = sA[cur];
    const bf16* B = sB[cur];
    bf16x8 a0 = *(const bf16x8*)(A + (wr * 32      + fr) * 32 + kg * 8);
    bf16x8 a1 = *(const bf16x8*)(A + (wr * 32 + 16 + fr) * 32 + kg * 8);
    bf16x8 b[4];
#pragma unroll
    for (int ni = 0; ni < 4; ++ni)
      b[ni] = ldfrag(B + (wc * 64 + ni * 16 + fr) * 36 + kg * 8);
#pragma unroll
    for (int ni = 0; ni < 4; ++ni) {
      acc[0][ni] = __builtin_amdgcn_mfma_f32_16x16x32_bf16(a0, b[ni], acc[0][ni], 0, 0, 0);
      acc[1][ni] = __builtin_amdgcn_mfma_f32_16x16x32_bf16(a1, b[ni], acc[1][ni], 0, 0, 0);
    }
    if (t + 1 < NT) WWRITE2(cur ^ 1);
    __syncthreads();
    cur ^= 1;
  }
#undef WLOAD2
#undef WWRITE2

#pragma unroll
  for (int mi = 0; mi < 2; ++mi) {
#pragma unroll
    for (int j = 0; j < 4; ++j) {
      int grow = rt * 64 + wr * 32 + mi * 16 + kg * 4 + j;
      if (grow < cnt) {
        float* orow = obuf + (size_t)slot[e * T_TOK + grow] * H_DIM + nb + wc * 64 + fr;
#pragma unroll
        for (int ni = 0; ni < 4; ++ni)
          orow[ni * 16] = acc[mi][ni][j];
      }
    }
  }
}

// ---------------- reduce: out[t] = sum_k obuf[t*4+k] + obuf[4096+t] ----------------
__global__ void reduce_kernel(const float* __restrict__ obuf, float* __restrict__ out) {
  const int t = blockIdx.x;
  const int c = threadIdx.x;
  const f32x4* o4 = (const f32x4*)obuf;
  f32x4 s = o4[(size_t)(t * 4 + 0) * 256 + c];
  s += o4[(size_t)(t * 4 + 1) * 256 + c];
  s += o4[(size_t)(t * 4 + 2) * 256 + c];
  s += o4[(size_t)(t * 4 + 3) * 256 + c];
  s += o4[(size_t)(T_TOK * TOPK + t) * 256 + c];
  ((f32x4*)out)[(size_t)t * 256 + c] = s;
}

extern "C" void kernel_launch(void* const* d_in, const int* in_sizes, int n_in,
                              void* d_out, int out_size, void* d_ws, size_t ws_size,
                              hipStream_t stream) {
  const float* x   = (const float*)d_in[0];
  const float* gw  = (const float*)d_in[1];
  const float* wgu = (const float*)d_in[2];
  const float* wd  = (const float*)d_in[3];
  const float* sgu = (const float*)d_in[4];
  const float* sd  = (const float*)d_in[5];
  float* out = (float*)d_out;

  char* ws = (char*)d_ws;
  int*   counts = (int*)  (ws);                 // 1 KB
  int*   tok    = (int*)  (ws + 1024);          // 68 KB
  float* wtA    = (float*)(ws + 70656);         // 68 KB
  int*   slotA  = (int*)  (ws + 140288);        // 68 KB
  int*   topk_e = (int*)  (ws + 209920);        // 16 KB
  float* topk_w = (float*)(ws + 226304);        // 16 KB
  bf16*  xb     = (bf16*) (ws + 245760);        // 2 MB
  bf16*  hbuf   = (bf16*) (ws + 2342912);       // 5.25 MB
  float* obuf   = (float*)(ws + 7585792);       // 20 MB fp32 [5120][1024]
  // total ws use ~28 MB

  prep_kernel<<<772, 256, 0, stream>>>(x, xb, gw, topk_e, topk_w, counts, tok, wtA, slotA);
  router_build_kernel<<<E_NUM, 256, 0, stream>>>(topk_e, topk_w, counts, tok, wtA, slotA);
  gemm1_kernel<<<dim3(8, 16, 17), 256, 0, stream>>>(xb, wgu, sgu, counts, tok, wtA, slotA, hbuf);
  gemm2_kernel<<<dim3(8, 16, 17), 256, 0, stream>>>(hbuf, wd, sd, counts, slotA, obuf);
  reduce_kernel<<<T_TOK, 256, 0, stream>>>(obuf, out);
}

// Round 13
// 97.510 us; speedup vs baseline: 1.3161x; 1.3161x over previous
//
#include <hip/hip_runtime.h>
#include <hip/hip_bf16.h>
#include <cstdint>

#define T_TOK 1024
#define H_DIM 1024
#define I_DIM 512
#define E_NUM 16
#define TOPK  4

typedef __bf16 bf16;
typedef __bf16 bf16x8 __attribute__((ext_vector_type(8)));
typedef float  f32x4  __attribute__((ext_vector_type(4)));

#define GLOAD16(g, l)                                                                   \
  __builtin_amdgcn_global_load_lds((const __attribute__((address_space(1))) void*)(g),  \
                                   (__attribute__((address_space(3))) void*)(l), 16, 0, 0)

// pack two floats -> u32 of two bf16 (lo = first)
__device__ __forceinline__ unsigned int pack2(float lo, float hi) {
  bf16 l = (bf16)lo, h = (bf16)hi;
  unsigned short ls, hs;
  __builtin_memcpy(&ls, &l, 2);
  __builtin_memcpy(&hs, &h, 2);
  return (unsigned int)ls | ((unsigned int)hs << 16);
}

// ---- no-LDS register transpose of a 64k x 64n tile: [K][N] fp32 -> [N][K] bf16 ----
// lane kp = k-pair, cg = 8-col group. Reads: 2x32B coalesced rows. Writes: for each
// j, 32 lanes store consecutive u32 -> full 128B line. No LDS, no barrier.
__device__ __forceinline__ void transpose_tile_reg(const float* __restrict__ src,
                                                   bf16* __restrict__ dst, int K, int N,
                                                   int kb, int nb, int wave, int lane) {
  const int kp = lane & 31;
  const int cg = wave * 2 + (lane >> 5);   // 0..7
  const float* s0 = src + (size_t)(kb + 2 * kp) * N + nb + cg * 8;
  float4 a0 = *(const float4*)(s0);
  float4 a1 = *(const float4*)(s0 + 4);
  float4 b0 = *(const float4*)(s0 + N);
  float4 b1 = *(const float4*)(s0 + N + 4);
  float r0[8] = {a0.x, a0.y, a0.z, a0.w, a1.x, a1.y, a1.z, a1.w};
  float r1[8] = {b0.x, b0.y, b0.z, b0.w, b1.x, b1.y, b1.z, b1.w};
  unsigned int* dbase = (unsigned int*)(dst + (size_t)(nb + cg * 8) * K + kb) + kp;
#pragma unroll
  for (int j = 0; j < 8; ++j)
    dbase[(size_t)j * (K / 2)] = pack2(r0[j], r1[j]);
}

// ================= fused prep kernel =================
// flat grid: [0,4352)    T1: wgu/sgu transpose (K=1024,N=1024)
//            [4352,6528) T2: wd/sd transpose  (K=512, N=1024)
//            [6528,7040) convx (512 blocks)
//            [7040,7296) router_score (256 blocks, 4 tokens each)
//            [7296,7300) init shared-expert lists
__global__ void prep_kernel(const float* __restrict__ x, bf16* __restrict__ xb,
                            const float* __restrict__ wgu, bf16* __restrict__ wguT,
                            const float* __restrict__ sgu, bf16* __restrict__ sguT,
                            const float* __restrict__ wd, bf16* __restrict__ wdT,
                            const float* __restrict__ sd, bf16* __restrict__ sdT,
                            const float* __restrict__ gw,
                            int* __restrict__ topk_e, float* __restrict__ topk_w,
                            int* __restrict__ counts, int* __restrict__ tok,
                            float* __restrict__ wt, int* __restrict__ slot) {
  const int b = blockIdx.x, tid = threadIdx.x;
  const int wave = tid >> 6, lane = tid & 63;

  if (b < 4352) {            // ---- T1
    const int z = b >> 8, r = b & 255;
    const float* src = (z < E_NUM) ? (wgu + (size_t)z * H_DIM * 2 * I_DIM) : sgu;
    bf16*       dst  = (z < E_NUM) ? (wguT + (size_t)z * H_DIM * 2 * I_DIM) : sguT;
    transpose_tile_reg(src, dst, H_DIM, 2 * I_DIM, (r >> 4) * 64, (r & 15) * 64, wave, lane);
  } else if (b < 6528) {     // ---- T2
    const int i = b - 4352, z = i >> 7, r = i & 127;
    const float* src = (z < E_NUM) ? (wd + (size_t)z * I_DIM * H_DIM) : sd;
    bf16*       dst  = (z < E_NUM) ? (wdT + (size_t)z * I_DIM * H_DIM) : sdT;
    transpose_tile_reg(src, dst, I_DIM, H_DIM, (r >> 4) * 64, (r & 15) * 64, wave, lane);
  } else if (b < 7040) {     // ---- convx
    const int i = (b - 6528) * 256 + tid;
    float4 f0 = ((const float4*)x)[i * 2];
    float4 f1 = ((const float4*)x)[i * 2 + 1];
    bf16x8 p;
    p[0]=(bf16)f0.x; p[1]=(bf16)f0.y; p[2]=(bf16)f0.z; p[3]=(bf16)f0.w;
    p[4]=(bf16)f1.x; p[5]=(bf16)f1.y; p[6]=(bf16)f1.z; p[7]=(bf16)f1.w;
    ((bf16x8*)xb)[i] = p;
  } else if (b < 7296) {     // ---- router_score
    const int t = (b - 7040) * 4 + wave;
    const float4* xr = (const float4*)(x + (size_t)t * H_DIM);
    float4 xv[4];
#pragma unroll
    for (int j = 0; j < 4; ++j) xv[j] = xr[lane + 64 * j];
    float p[E_NUM];
#pragma unroll
    for (int e = 0; e < E_NUM; ++e) {
      const float4* gr = (const float4*)(gw + (size_t)e * H_DIM);
      float s = 0.f;
#pragma unroll
      for (int j = 0; j < 4; ++j) {
        float4 g = gr[lane + 64 * j];
        s += xv[j].x * g.x + xv[j].y * g.y + xv[j].z * g.z + xv[j].w * g.w;
      }
      p[e] = s;
    }
#pragma unroll
    for (int off = 32; off > 0; off >>= 1) {
#pragma unroll
      for (int e = 0; e < E_NUM; ++e) p[e] += __shfl_xor(p[e], off);
    }
    float rem[E_NUM];
#pragma unroll
    for (int e = 0; e < E_NUM; ++e) rem[e] = 1.f / (1.f + __expf(-p[e]));
    float vals[TOPK]; int idx[TOPK];
#pragma unroll
    for (int k = 0; k < TOPK; ++k) {
      float m = rem[0]; int mi = 0;
#pragma unroll
      for (int e = 1; e < E_NUM; ++e) {
        if (rem[e] > m) { m = rem[e]; mi = e; }
      }
      vals[k] = m; idx[k] = mi;
#pragma unroll
      for (int e = 0; e < E_NUM; ++e) rem[e] = (e == mi) ? -1e30f : rem[e];
    }
    if (lane == 0) {
      float inv = 1.f / (vals[0] + vals[1] + vals[2] + vals[3]);
      int4 ids; ids.x = idx[0]; ids.y = idx[1]; ids.z = idx[2]; ids.w = idx[3];
      float4 w4; w4.x = vals[0]*inv; w4.y = vals[1]*inv; w4.z = vals[2]*inv; w4.w = vals[3]*inv;
      ((int4*)topk_e)[t] = ids;
      ((float4*)topk_w)[t] = w4;
    }
  } else {                   // ---- init shared-expert list
    const int i = (b - 7296) * 256 + tid;
    if (i == 0) counts[E_NUM] = T_TOK;
    tok [E_NUM * T_TOK + i] = i;
    wt  [E_NUM * T_TOK + i] = 1.0f;
    slot[E_NUM * T_TOK + i] = T_TOK * TOPK + i;
  }
}

// ---------------- router phase 2: per-expert list build via ballot prefix ----------------
__global__ void router_build_kernel(const int* __restrict__ topk_e, const float* __restrict__ topk_w,
                                    int* __restrict__ counts, int* __restrict__ tok,
                                    float* __restrict__ wt, int* __restrict__ slot) {
  const int e = blockIdx.x;  // 0..15
  const int tid = threadIdx.x, wave = tid >> 6, lane = tid & 63;
  __shared__ int wsum[4];
  int base = 0;
  for (int r = 0; r < 4; ++r) {
    int t = r * 256 + tid;
    int4 ids = ((const int4*)topk_e)[t];
    int match = -1;
    if (ids.x == e) match = 0;
    if (ids.y == e) match = 1;
    if (ids.z == e) match = 2;
    if (ids.w == e) match = 3;
    unsigned long long bm = __ballot(match >= 0);
    int prefix = __popcll(bm & ((1ull << lane) - 1ull));
    if (lane == 0) wsum[wave] = __popcll(bm);
    __syncthreads();
    int wbase = 0;
#pragma unroll
    for (int wv = 0; wv < 4; ++wv) wbase += (wv < wave) ? wsum[wv] : 0;
    int total = wsum[0] + wsum[1] + wsum[2] + wsum[3];
    if (match >= 0) {
      int pos = base + wbase + prefix;
      tok [e * T_TOK + pos] = t;
      wt  [e * T_TOK + pos] = topk_w[t * 4 + match];
      slot[e * T_TOK + pos] = t * 4 + match;
    }
    base += total;
    __syncthreads();
  }
  if (tid == 0) counts[e] = base;
}

// ---------------- GEMM1: Xb gathered @ WguT -> wt*swiglu -> h bf16 ----------------
// BM=64, BN=64(g)+64(u), BK=32, 4 waves (2x2). 3-buffer counted-vmcnt pipeline:
// stage t+2 issued BEFORE waiting vmcnt(6) -> 2 compute phases of latency cover.
__global__ __launch_bounds__(256, 4)
void gemm1_kernel(const bf16* __restrict__ xb, const bf16* __restrict__ wguT,
                  const bf16* __restrict__ sguT, const int* __restrict__ counts,
                  const int* __restrict__ tok, const float* __restrict__ wt,
                  const int* __restrict__ slot, bf16* __restrict__ hbuf) {
  const int e   = blockIdx.z;
  const int cnt = counts[e];
  const int rt  = blockIdx.y;
  if (rt * 64 >= cnt) return;
  const int nb = blockIdx.x * 64;
  const bf16* BT = (e < E_NUM) ? (wguT + (size_t)e * (2 * I_DIM) * H_DIM) : sguT;

  __shared__ __align__(16) bf16 sA[3][64 * 32];
  __shared__ __align__(16) bf16 sG[3][64 * 32];
  __shared__ __align__(16) bf16 sU[3][64 * 32];

  const int tid = threadIdx.x, wave = tid >> 6, lane = tid & 63;
  const int wr = wave >> 1, wc = wave & 1;
  const int fr = lane & 15, kg = lane >> 4;
  const int lr = lane >> 2, lk = (lane & 3) * 8;

  int ar = rt * 64 + wave * 16 + lr;
  int arc = ar < cnt ? ar : cnt - 1;
  const bf16* aS = xb + (size_t)tok[e * T_TOK + arc] * H_DIM + lk;
  const bf16* gS = BT + (size_t)(nb + wave * 16 + lr) * H_DIM + lk;
  const bf16* uS = BT + (size_t)(I_DIM + nb + wave * 16 + lr) * H_DIM + lk;
  const int ldsOff = wave * 512;

  f32x4 accg[2][2], accu[2][2];
#pragma unroll
  for (int i = 0; i < 2; ++i)
#pragma unroll
    for (int j = 0; j < 2; ++j) { accg[i][j] = f32x4{0,0,0,0}; accu[i][j] = f32x4{0,0,0,0}; }

#define STG1(t, bidx) do { int ko = (t) * 32;   \
    GLOAD16(aS + ko, sA[bidx] + ldsOff);        \
    GLOAD16(gS + ko, sG[bidx] + ldsOff);        \
    GLOAD16(uS + ko, sU[bidx] + ldsOff); } while (0)

  STG1(0, 0); STG1(1, 1);
  const int NT = H_DIM / 32;  // 32
  int bufc = 0;
  for (int t = 0; t < NT; ++t) {
    int bn = bufc + 2; bn = bn >= 3 ? bn - 3 : bn;
    if (t + 2 < NT) {
      STG1(t + 2, bn);
      asm volatile("s_waitcnt vmcnt(6)" ::: "memory");   // tile t done; t+1,t+2 in flight
    } else if (t + 1 < NT) {
      asm volatile("s_waitcnt vmcnt(3)" ::: "memory");
    } else {
      asm volatile("s_waitcnt vmcnt(0)" ::: "memory");
    }
    __builtin_amdgcn_s_barrier();
    __builtin_amdgcn_sched_barrier(0);
    const bf16* A = sA[bufc];
    const bf16* G = sG[bufc];
    const bf16* U = sU[bufc];
    bf16x8 a0 = *(const bf16x8*)(A + (wr * 32      + fr) * 32 + kg * 8);
    bf16x8 a1 = *(const bf16x8*)(A + (wr * 32 + 16 + fr) * 32 + kg * 8);
    bf16x8 g0 = *(const bf16x8*)(G + (wc * 32      + fr) * 32 + kg * 8);
    bf16x8 g1 = *(const bf16x8*)(G + (wc * 32 + 16 + fr) * 32 + kg * 8);
    bf16x8 u0 = *(const bf16x8*)(U + (wc * 32      + fr) * 32 + kg * 8);
    bf16x8 u1 = *(const bf16x8*)(U + (wc * 32 + 16 + fr) * 32 + kg * 8);
    accg[0][0] = __builtin_amdgcn_mfma_f32_16x16x32_bf16(a0, g0, accg[0][0], 0, 0, 0);
    accg[0][1] = __builtin_amdgcn_mfma_f32_16x16x32_bf16(a0, g1, accg[0][1], 0, 0, 0);
    accg[1][0] = __builtin_amdgcn_mfma_f32_16x16x32_bf16(a1, g0, accg[1][0], 0, 0, 0);
    accg[1][1] = __builtin_amdgcn_mfma_f32_16x16x32_bf16(a1, g1, accg[1][1], 0, 0, 0);
    accu[0][0] = __builtin_amdgcn_mfma_f32_16x16x32_bf16(a0, u0, accu[0][0], 0, 0, 0);
    accu[0][1] = __builtin_amdgcn_mfma_f32_16x16x32_bf16(a0, u1, accu[0][1], 0, 0, 0);
    accu[1][0] = __builtin_amdgcn_mfma_f32_16x16x32_bf16(a1, u0, accu[1][0], 0, 0, 0);
    accu[1][1] = __builtin_amdgcn_mfma_f32_16x16x32_bf16(a1, u1, accu[1][1], 0, 0, 0);
    __builtin_amdgcn_sched_barrier(0);
    __builtin_amdgcn_s_barrier();
    bufc = bufc == 2 ? 0 : bufc + 1;
  }
#undef STG1

#pragma unroll
  for (int mi = 0; mi < 2; ++mi) {
#pragma unroll
    for (int j = 0; j < 4; ++j) {
      int grow = rt * 64 + wr * 32 + mi * 16 + kg * 4 + j;
      if (grow < cnt) {
        bf16* hr = hbuf + (size_t)slot[e * T_TOK + grow] * I_DIM;
        float w = wt[e * T_TOK + grow];
#pragma unroll
        for (int ni = 0; ni < 2; ++ni) {
          float g = accg[mi][ni][j], u = accu[mi][ni][j];
          float h = w * (g / (1.f + __expf(-g))) * u;
          hr[nb + wc * 32 + ni * 16 + fr] = (bf16)h;
        }
      }
    }
  }
}

// ---------------- GEMM2: h gathered @ WdT -> plain stores into obuf[slot] ----------------
// BM=64, BN=128, BK=32, 3-buffer counted-vmcnt pipeline.
__global__ __launch_bounds__(256, 4)
void gemm2_kernel(const bf16* __restrict__ hbuf, const bf16* __restrict__ wdT,
                  const bf16* __restrict__ sdT, const int* __restrict__ counts,
                  const int* __restrict__ slot, float* __restrict__ obuf) {
  const int e   = blockIdx.z;
  const int cnt = counts[e];
  const int rt  = blockIdx.y;
  if (rt * 64 >= cnt) return;
  const int nb = blockIdx.x * 128;
  const bf16* BT = (e < E_NUM) ? (wdT + (size_t)e * H_DIM * I_DIM) : sdT;

  __shared__ __align__(16) bf16 sA[3][64 * 32];
  __shared__ __align__(16) bf16 sB[3][128 * 32];

  const int tid = threadIdx.x, wave = tid >> 6, lane = tid & 63;
  const int wr = wave >> 1, wc = wave & 1;
  const int fr = lane & 15, kg = lane >> 4;
  const int lr = lane >> 2, lk = (lane & 3) * 8;

  int ar = rt * 64 + wave * 16 + lr;
  int arc = ar < cnt ? ar : cnt - 1;
  const bf16* aS  = hbuf + (size_t)slot[e * T_TOK + arc] * I_DIM + lk;
  const bf16* bS0 = BT + (size_t)(nb + wave * 32 + lr) * I_DIM + lk;
  const bf16* bS1 = bS0 + (size_t)16 * I_DIM;
  const int aOff  = wave * 512;
  const int bOff0 = wave * 1024;
  const int bOff1 = bOff0 + 512;

  f32x4 acc[2][4];
#pragma unroll
  for (int i = 0; i < 2; ++i)
#pragma unroll
    for (int j = 0; j < 4; ++j) acc[i][j] = f32x4{0,0,0,0};

#define STG2(t, bidx) do { int ko = (t) * 32;   \
    GLOAD16(aS  + ko, sA[bidx] + aOff);         \
    GLOAD16(bS0 + ko, sB[bidx] + bOff0);        \
    GLOAD16(bS1 + ko, sB[bidx] + bOff1); } while (0)

  STG2(0, 0); STG2(1, 1);
  const int NT = I_DIM / 32;  // 16
  int bufc = 0;
  for (int t = 0; t < NT; ++t) {
    int bn = bufc + 2; bn = bn >= 3 ? bn - 3 : bn;
    if (t + 2 < NT) {
      STG2(t + 2, bn);
      asm volatile("s_waitcnt vmcnt(6)" ::: "memory");
    } else if (t + 1 < NT) {
      asm volatile("s_waitcnt vmcnt(3)" ::: "memory");
    } else {
      asm volatile("s_waitcnt vmcnt(0)" ::: "memory");
    }
    __builtin_amdgcn_s_barrier();
    __builtin_amdgcn_sched_barrier(0);
    const bf16* A = sA[bufc];
    const bf16* B = sB[bufc];
    bf16x8 a0 = *(const bf16x8*)(A + (wr * 32      + fr) * 32 + kg * 8);
    bf16x8 a1 = *(const bf16x8*)(A + (wr * 32 + 16 + fr) * 32 + kg * 8);
    bf16x8 b[4];
#pragma unroll
    for (int ni = 0; ni < 4; ++ni)
      b[ni] = *(const bf16x8*)(B + (wc * 64 + ni * 16 + fr) * 32 + kg * 8);
#pragma unroll
    for (int ni = 0; ni < 4; ++ni) {
      acc[0][ni] = __builtin_amdgcn_mfma_f32_16x16x32_bf16(a0, b[ni], acc[0][ni], 0, 0, 0);
      acc[1][ni] = __builtin_amdgcn_mfma_f32_16x16x32_bf16(a1, b[ni], acc[1][ni], 0, 0, 0);
    }
    __builtin_amdgcn_sched_barrier(0);
    __builtin_amdgcn_s_barrier();
    bufc = bufc == 2 ? 0 : bufc + 1;
  }
#undef STG2

#pragma unroll
  for (int mi = 0; mi < 2; ++mi) {
#pragma unroll
    for (int j = 0; j < 4; ++j) {
      int grow = rt * 64 + wr * 32 + mi * 16 + kg * 4 + j;
      if (grow < cnt) {
        float* orow = obuf + (size_t)slot[e * T_TOK + grow] * H_DIM + nb + wc * 64 + fr;
#pragma unroll
        for (int ni = 0; ni < 4; ++ni)
          orow[ni * 16] = acc[mi][ni][j];
      }
    }
  }
}

// ---------------- reduce: out[t] = sum_k obuf[t*4+k] + obuf[4096+t] ----------------
__global__ void reduce_kernel(const float* __restrict__ obuf, float* __restrict__ out) {
  const int t = blockIdx.x;
  const int c = threadIdx.x;
  const f32x4* o4 = (const f32x4*)obuf;
  f32x4 s = o4[(size_t)(t * 4 + 0) * 256 + c];
  s += o4[(size_t)(t * 4 + 1) * 256 + c];
  s += o4[(size_t)(t * 4 + 2) * 256 + c];
  s += o4[(size_t)(t * 4 + 3) * 256 + c];
  s += o4[(size_t)(T_TOK * TOPK + t) * 256 + c];
  ((f32x4*)out)[(size_t)t * 256 + c] = s;
}

extern "C" void kernel_launch(void* const* d_in, const int* in_sizes, int n_in,
                              void* d_out, int out_size, void* d_ws, size_t ws_size,
                              hipStream_t stream) {
  const float* x   = (const float*)d_in[0];
  const float* gw  = (const float*)d_in[1];
  const float* wgu = (const float*)d_in[2];
  const float* wd  = (const float*)d_in[3];
  const float* sgu = (const float*)d_in[4];
  const float* sd  = (const float*)d_in[5];
  float* out = (float*)d_out;

  char* ws = (char*)d_ws;
  int*   counts = (int*)  (ws);                 // 1 KB
  int*   tok    = (int*)  (ws + 1024);          // 68 KB
  float* wtA    = (float*)(ws + 70656);         // 68 KB
  int*   slotA  = (int*)  (ws + 140288);        // 68 KB
  int*   topk_e = (int*)  (ws + 209920);        // 16 KB
  float* topk_w = (float*)(ws + 226304);        // 16 KB
  bf16*  xb     = (bf16*) (ws + 245760);        // 2 MB
  bf16*  hbuf   = (bf16*) (ws + 2342912);       // 5.25 MB
  bf16*  wguT   = (bf16*) (ws + 7585792);       // 32 MB  [E][2I][H]
  bf16*  wdT    = (bf16*) (ws + 41140224);      // 16 MB  [E][H][I]
  bf16*  sguT   = (bf16*) (ws + 57917440);      // 2 MB   [2I][H]
  bf16*  sdT    = (bf16*) (ws + 60014592);      // 1 MB   [H][I]
  // obuf (20 MB fp32 [5120][1024]) aliases wguT: dead after gemm1, rewritten by
  // prep before gemm1 on every call.
  float* obuf   = (float*)(ws + 7585792);

  prep_kernel<<<7300, 256, 0, stream>>>(x, xb, wgu, wguT, sgu, sguT, wd, wdT, sd, sdT,
                                        gw, topk_e, topk_w, counts, tok, wtA, slotA);
  router_build_kernel<<<E_NUM, 256, 0, stream>>>(topk_e, topk_w, counts, tok, wtA, slotA);
  gemm1_kernel<<<dim3(8, 16, 17), 256, 0, stream>>>(xb, wguT, sguT, counts, tok, wtA, slotA, hbuf);
  gemm2_kernel<<<dim3(8, 16, 17), 256, 0, stream>>>(hbuf, wdT, sdT, counts, slotA, obuf);
  reduce_kernel<<<T_TOK, 256, 0, stream>>>(obuf, out);
}

// Round 14
// 97.441 us; speedup vs baseline: 1.3170x; 1.0007x over previous
//
#include <hip/hip_runtime.h>
#include <hip/hip_bf16.h>
#include <cstdint>

#define T_TOK 1024
#define H_DIM 1024
#define I_DIM 512
#define E_NUM 16
#define TOPK  4

typedef __bf16 bf16;
typedef __bf16 bf16x4 __attribute__((ext_vector_type(4)));
typedef __bf16 bf16x8 __attribute__((ext_vector_type(8)));
typedef float  f32x4  __attribute__((ext_vector_type(4)));

#define GLOAD16(g, l)                                                                   \
  __builtin_amdgcn_global_load_lds((const __attribute__((address_space(1))) void*)(g),  \
                                   (__attribute__((address_space(3))) void*)(l), 16, 0, 0)

__device__ __forceinline__ unsigned lds_addr(const bf16* p) {
  return (unsigned)(uintptr_t)(const __attribute__((address_space(3))) bf16*)p;
}

// hardware transpose read: lane l receives column (l&15) (4 bf16, rows j=0..3) of the
// 4x16 subtile whose 16 lanes supply base + (l&15)*8 bytes. OFF walks k-subtiles.
template <int OFF>
__device__ __forceinline__ bf16x4 tr_read(unsigned addr) {
  bf16x4 r;
  if constexpr (OFF == 0)
    asm volatile("ds_read_b64_tr_b16 %0, %1" : "=v"(r) : "v"(addr));
  else if constexpr (OFF == 512)
    asm volatile("ds_read_b64_tr_b16 %0, %1 offset:512" : "=v"(r) : "v"(addr));
  else
    asm volatile("ds_read_b64_tr_b16 %0, %1 offset:1024" : "=v"(r) : "v"(addr));
  return r;
}

__device__ __forceinline__ bf16x8 cat8(bf16x4 a, bf16x4 b) {
  return __builtin_shufflevector(a, b, 0, 1, 2, 3, 4, 5, 6, 7);
}

// ================= fused prep: PURE STREAMING convert (no transpose) =================
// [0,8192)      wgu  -> wguB   (16M floats)
// [8192,12288)  wd   -> wdB    (8M)
// [12288,12800) sgu  -> sguB   (1M)
// [12800,13056) sd   -> sdB    (0.5M)
// [13056,13568) x    -> xb     (1M)
// [13568,13824) router_score
// [13824,13828) init shared-expert lists
__device__ __forceinline__ void conv8(const float* __restrict__ src, bf16* __restrict__ dst,
                                      int i) {
  float4 f0 = ((const float4*)src)[i * 2];
  float4 f1 = ((const float4*)src)[i * 2 + 1];
  bf16x8 p;
  p[0]=(bf16)f0.x; p[1]=(bf16)f0.y; p[2]=(bf16)f0.z; p[3]=(bf16)f0.w;
  p[4]=(bf16)f1.x; p[5]=(bf16)f1.y; p[6]=(bf16)f1.z; p[7]=(bf16)f1.w;
  ((bf16x8*)dst)[i] = p;
}

__global__ void prep_kernel(const float* __restrict__ x, bf16* __restrict__ xb,
                            const float* __restrict__ wgu, bf16* __restrict__ wguB,
                            const float* __restrict__ wd, bf16* __restrict__ wdB,
                            const float* __restrict__ sgu, bf16* __restrict__ sguB,
                            const float* __restrict__ sd, bf16* __restrict__ sdB,
                            const float* __restrict__ gw,
                            int* __restrict__ topk_e, float* __restrict__ topk_w,
                            int* __restrict__ counts, int* __restrict__ tok,
                            float* __restrict__ wt, int* __restrict__ slot) {
  const int b = blockIdx.x, tid = threadIdx.x;
  if (b < 8192)        conv8(wgu, wguB, b * 256 + tid);
  else if (b < 12288)  conv8(wd, wdB, (b - 8192) * 256 + tid);
  else if (b < 12800)  conv8(sgu, sguB, (b - 12288) * 256 + tid);
  else if (b < 13056)  conv8(sd, sdB, (b - 12800) * 256 + tid);
  else if (b < 13568)  conv8(x, xb, (b - 13056) * 256 + tid);
  else if (b < 13824) {  // ---- router_score
    const int wave = tid >> 6, lane = tid & 63;
    const int t = (b - 13568) * 4 + wave;
    const float4* xr = (const float4*)(x + (size_t)t * H_DIM);
    float4 xv[4];
#pragma unroll
    for (int j = 0; j < 4; ++j) xv[j] = xr[lane + 64 * j];
    float p[E_NUM];
#pragma unroll
    for (int e = 0; e < E_NUM; ++e) {
      const float4* gr = (const float4*)(gw + (size_t)e * H_DIM);
      float s = 0.f;
#pragma unroll
      for (int j = 0; j < 4; ++j) {
        float4 g = gr[lane + 64 * j];
        s += xv[j].x * g.x + xv[j].y * g.y + xv[j].z * g.z + xv[j].w * g.w;
      }
      p[e] = s;
    }
#pragma unroll
    for (int off = 32; off > 0; off >>= 1) {
#pragma unroll
      for (int e = 0; e < E_NUM; ++e) p[e] += __shfl_xor(p[e], off);
    }
    float rem[E_NUM];
#pragma unroll
    for (int e = 0; e < E_NUM; ++e) rem[e] = 1.f / (1.f + __expf(-p[e]));
    float vals[TOPK]; int idx[TOPK];
#pragma unroll
    for (int k = 0; k < TOPK; ++k) {
      float m = rem[0]; int mi = 0;
#pragma unroll
      for (int e = 1; e < E_NUM; ++e) {
        if (rem[e] > m) { m = rem[e]; mi = e; }
      }
      vals[k] = m; idx[k] = mi;
#pragma unroll
      for (int e = 0; e < E_NUM; ++e) rem[e] = (e == mi) ? -1e30f : rem[e];
    }
    if (lane == 0) {
      float inv = 1.f / (vals[0] + vals[1] + vals[2] + vals[3]);
      int4 ids; ids.x = idx[0]; ids.y = idx[1]; ids.z = idx[2]; ids.w = idx[3];
      float4 w4; w4.x = vals[0]*inv; w4.y = vals[1]*inv; w4.z = vals[2]*inv; w4.w = vals[3]*inv;
      ((int4*)topk_e)[t] = ids;
      ((float4*)topk_w)[t] = w4;
    }
  } else {               // ---- init shared-expert list
    const int i = (b - 13824) * 256 + tid;
    if (i == 0) counts[E_NUM] = T_TOK;
    tok [E_NUM * T_TOK + i] = i;
    wt  [E_NUM * T_TOK + i] = 1.0f;
    slot[E_NUM * T_TOK + i] = T_TOK * TOPK + i;
  }
}

// ---------------- router phase 2: per-expert list build via ballot prefix ----------------
__global__ void router_build_kernel(const int* __restrict__ topk_e, const float* __restrict__ topk_w,
                                    int* __restrict__ counts, int* __restrict__ tok,
                                    float* __restrict__ wt, int* __restrict__ slot) {
  const int e = blockIdx.x;
  const int tid = threadIdx.x, wave = tid >> 6, lane = tid & 63;
  __shared__ int wsum[4];
  int base = 0;
  for (int r = 0; r < 4; ++r) {
    int t = r * 256 + tid;
    int4 ids = ((const int4*)topk_e)[t];
    int match = -1;
    if (ids.x == e) match = 0;
    if (ids.y == e) match = 1;
    if (ids.z == e) match = 2;
    if (ids.w == e) match = 3;
    unsigned long long bm = __ballot(match >= 0);
    int prefix = __popcll(bm & ((1ull << lane) - 1ull));
    if (lane == 0) wsum[wave] = __popcll(bm);
    __syncthreads();
    int wbase = 0;
#pragma unroll
    for (int wv = 0; wv < 4; ++wv) wbase += (wv < wave) ? wsum[wv] : 0;
    int total = wsum[0] + wsum[1] + wsum[2] + wsum[3];
    if (match >= 0) {
      int pos = base + wbase + prefix;
      tok [e * T_TOK + pos] = t;
      wt  [e * T_TOK + pos] = topk_w[t * 4 + match];
      slot[e * T_TOK + pos] = t * 4 + match;
    }
    base += total;
    __syncthreads();
  }
  if (tid == 0) counts[e] = base;
}

// ---------------- GEMM1: Xb gathered @ Wgu(natural bf16) -> wt*swiglu -> h ----------------
// W staged into subtiled LDS [ksub 8][nblk 4][4][16] via linear gload_lds with
// coalesced-per-line subtile-ordered sources; B-fragments via ds_read_b64_tr_b16.
__global__ __launch_bounds__(256, 4)
void gemm1_kernel(const bf16* __restrict__ xb, const bf16* __restrict__ wguB,
                  const bf16* __restrict__ sguB, const int* __restrict__ counts,
                  const int* __restrict__ tok, const float* __restrict__ wt,
                  const int* __restrict__ slot, bf16* __restrict__ hbuf) {
  const int e   = blockIdx.z;
  const int cnt = counts[e];
  const int rt  = blockIdx.y;
  if (rt * 64 >= cnt) return;
  const int nb = blockIdx.x * 64;
  const bf16* WB = (e < E_NUM) ? (wguB + (size_t)e * H_DIM * (2 * I_DIM)) : sguB;  // [1024][1024]

  __shared__ __align__(16) bf16 sA[3][64 * 32];   // [m][k] linear
  __shared__ __align__(16) bf16 sG[3][2048];      // [ksub8][nblk4][4][16]
  __shared__ __align__(16) bf16 sU[3][2048];

  const int tid = threadIdx.x, wave = tid >> 6, lane = tid & 63;
  const int wr = wave >> 1, wc = wave & 1;
  const int fr = lane & 15, kg = lane >> 4;
  const int lr = lane >> 2, lk = (lane & 3) * 8;

  int ar = rt * 64 + wave * 16 + lr;
  int arc = ar < cnt ? ar : cnt - 1;
  const bf16* aS = xb + (size_t)tok[e * T_TOK + arc] * H_DIM + lk;
  const int aOff = wave * 512;

  // W staging source: unit u = wave*64+lane of subtiled order -> (k,n) in natural layout
  const int k_off = 8 * wave + 4 * (lane >> 5) + ((lane & 7) >> 1);
  const int n_off = 16 * ((lane >> 3) & 3) + 8 * (lane & 1);
  const bf16* gS = WB + (size_t)k_off * (2 * I_DIM) + nb + n_off;
  const bf16* uS = WB + (size_t)k_off * (2 * I_DIM) + I_DIM + nb + n_off;
  const int wOff = wave * 512;

  f32x4 accg[2][2], accu[2][2];
#pragma unroll
  for (int i = 0; i < 2; ++i)
#pragma unroll
    for (int j = 0; j < 2; ++j) { accg[i][j] = f32x4{0,0,0,0}; accu[i][j] = f32x4{0,0,0,0}; }

#define STG1(t, bidx) do { size_t ko = (size_t)(t) * 32;    \
    GLOAD16(aS + ko, sA[bidx] + aOff);                      \
    GLOAD16(gS + ko * (2 * I_DIM), sG[bidx] + wOff);        \
    GLOAD16(uS + ko * (2 * I_DIM), sU[bidx] + wOff); } while (0)

  STG1(0, 0); STG1(1, 1);
  const int NT = H_DIM / 32;  // 32
  int bufc = 0;
  for (int t = 0; t < NT; ++t) {
    int bn = bufc + 2; bn = bn >= 3 ? bn - 3 : bn;
    if (t + 2 < NT) {
      STG1(t + 2, bn);
      asm volatile("s_waitcnt vmcnt(6)" ::: "memory");
    } else if (t + 1 < NT) {
      asm volatile("s_waitcnt vmcnt(3)" ::: "memory");
    } else {
      asm volatile("s_waitcnt vmcnt(0)" ::: "memory");
    }
    __builtin_amdgcn_s_barrier();
    __builtin_amdgcn_sched_barrier(0);
    const bf16* A = sA[bufc];
    bf16x8 a0 = *(const bf16x8*)(A + (wr * 32      + fr) * 32 + kg * 8);
    bf16x8 a1 = *(const bf16x8*)(A + (wr * 32 + 16 + fr) * 32 + kg * 8);
    // tr-read B fragments: group kg at subtile (2kg)*4+nblk -> byte kg*1024 + nblk*128
    unsigned gb = lds_addr(sG[bufc]) + (unsigned)((lane >> 4) << 10) + (unsigned)((lane & 15) << 3);
    unsigned ub = lds_addr(sU[bufc]) + (unsigned)((lane >> 4) << 10) + (unsigned)((lane & 15) << 3);
    unsigned nb0 = (unsigned)(wc * 256), nb1 = nb0 + 128;
    bf16x8 g0 = cat8(tr_read<0>(gb + nb0), tr_read<512>(gb + nb0));
    bf16x8 g1 = cat8(tr_read<0>(gb + nb1), tr_read<512>(gb + nb1));
    bf16x8 u0 = cat8(tr_read<0>(ub + nb0), tr_read<512>(ub + nb0));
    bf16x8 u1 = cat8(tr_read<0>(ub + nb1), tr_read<512>(ub + nb1));
    asm volatile("s_waitcnt lgkmcnt(0)" ::: "memory");
    __builtin_amdgcn_sched_barrier(0);
    accg[0][0] = __builtin_amdgcn_mfma_f32_16x16x32_bf16(a0, g0, accg[0][0], 0, 0, 0);
    accg[0][1] = __builtin_amdgcn_mfma_f32_16x16x32_bf16(a0, g1, accg[0][1], 0, 0, 0);
    accg[1][0] = __builtin_amdgcn_mfma_f32_16x16x32_bf16(a1, g0, accg[1][0], 0, 0, 0);
    accg[1][1] = __builtin_amdgcn_mfma_f32_16x16x32_bf16(a1, g1, accg[1][1], 0, 0, 0);
    accu[0][0] = __builtin_amdgcn_mfma_f32_16x16x32_bf16(a0, u0, accu[0][0], 0, 0, 0);
    accu[0][1] = __builtin_amdgcn_mfma_f32_16x16x32_bf16(a0, u1, accu[0][1], 0, 0, 0);
    accu[1][0] = __builtin_amdgcn_mfma_f32_16x16x32_bf16(a1, u0, accu[1][0], 0, 0, 0);
    accu[1][1] = __builtin_amdgcn_mfma_f32_16x16x32_bf16(a1, u1, accu[1][1], 0, 0, 0);
    __builtin_amdgcn_sched_barrier(0);
    __builtin_amdgcn_s_barrier();
    bufc = bufc == 2 ? 0 : bufc + 1;
  }
#undef STG1

#pragma unroll
  for (int mi = 0; mi < 2; ++mi) {
#pragma unroll
    for (int j = 0; j < 4; ++j) {
      int grow = rt * 64 + wr * 32 + mi * 16 + kg * 4 + j;
      if (grow < cnt) {
        bf16* hr = hbuf + (size_t)slot[e * T_TOK + grow] * I_DIM;
        float w = wt[e * T_TOK + grow];
#pragma unroll
        for (int ni = 0; ni < 2; ++ni) {
          float g = accg[mi][ni][j], u = accu[mi][ni][j];
          float h = w * (g / (1.f + __expf(-g))) * u;
          hr[nb + wc * 32 + ni * 16 + fr] = (bf16)h;
        }
      }
    }
  }
}

// ---------------- GEMM2: h gathered @ Wd(natural bf16) -> plain stores into obuf ----------------
// W tile 32k x 128n staged as [ksub 8][nblk 8][4][16]; tr-read fragments.
__global__ __launch_bounds__(256, 4)
void gemm2_kernel(const bf16* __restrict__ hbuf, const bf16* __restrict__ wdB,
                  const bf16* __restrict__ sdB, const int* __restrict__ counts,
                  const int* __restrict__ slot, float* __restrict__ obuf) {
  const int e   = blockIdx.z;
  const int cnt = counts[e];
  const int rt  = blockIdx.y;
  if (rt * 64 >= cnt) return;
  const int nb = blockIdx.x * 128;
  const bf16* WB = (e < E_NUM) ? (wdB + (size_t)e * I_DIM * H_DIM) : sdB;  // [512][1024]

  __shared__ __align__(16) bf16 sA[3][64 * 32];
  __shared__ __align__(16) bf16 sB[3][4096];   // [ksub8][nblk8][4][16]

  const int tid = threadIdx.x, wave = tid >> 6, lane = tid & 63;
  const int wr = wave >> 1, wc = wave & 1;
  const int fr = lane & 15, kg = lane >> 4;
  const int lr = lane >> 2, lk = (lane & 3) * 8;

  int ar = rt * 64 + wave * 16 + lr;
  int arc = ar < cnt ? ar : cnt - 1;
  const bf16* aS = hbuf + (size_t)slot[e * T_TOK + arc] * I_DIM + lk;
  const int aOff = wave * 512;

  // W staging: two instrs per wave (r=0,1): unit u = wave*128 + r*64 + lane
  const int j2 = (lane & 7) >> 1, h2 = lane & 1, nblk2 = lane >> 3;
  const int n2 = nb + nblk2 * 16 + 8 * h2;
  const bf16* bS0 = WB + (size_t)((wave * 2 + 0) * 4 + j2) * H_DIM + n2;
  const bf16* bS1 = WB + (size_t)((wave * 2 + 1) * 4 + j2) * H_DIM + n2;
  const int bOff0 = wave * 1024;
  const int bOff1 = bOff0 + 512;

  f32x4 acc[2][4];
#pragma unroll
  for (int i = 0; i < 2; ++i)
#pragma unroll
    for (int j = 0; j < 4; ++j) acc[i][j] = f32x4{0,0,0,0};

#define STG2(t, bidx) do { size_t ko = (size_t)(t) * 32;    \
    GLOAD16(aS + ko, sA[bidx] + aOff);                      \
    GLOAD16(bS0 + ko * H_DIM, sB[bidx] + bOff0);            \
    GLOAD16(bS1 + ko * H_DIM, sB[bidx] + bOff1); } while (0)

  STG2(0, 0); STG2(1, 1);
  const int NT = I_DIM / 32;  // 16
  int bufc = 0;
  for (int t = 0; t < NT; ++t) {
    int bn = bufc + 2; bn = bn >= 3 ? bn - 3 : bn;
    if (t + 2 < NT) {
      STG2(t + 2, bn);
      asm volatile("s_waitcnt vmcnt(6)" ::: "memory");
    } else if (t + 1 < NT) {
      asm volatile("s_waitcnt vmcnt(3)" ::: "memory");
    } else {
      asm volatile("s_waitcnt vmcnt(0)" ::: "memory");
    }
    __builtin_amdgcn_s_barrier();
    __builtin_amdgcn_sched_barrier(0);
    const bf16* A = sA[bufc];
    bf16x8 a0 = *(const bf16x8*)(A + (wr * 32      + fr) * 32 + kg * 8);
    bf16x8 a1 = *(const bf16x8*)(A + (wr * 32 + 16 + fr) * 32 + kg * 8);
    // group kg subtile base: kg*2048 bytes; nblk = wc*4 + ni at +nblk*128
    unsigned bb = lds_addr(sB[bufc]) + (unsigned)((lane >> 4) << 11) + (unsigned)((lane & 15) << 3)
                + (unsigned)(wc * 512);
    bf16x8 b[4];
#pragma unroll
    for (int ni = 0; ni < 4; ++ni)
      b[ni] = cat8(tr_read<0>(bb + ni * 128), tr_read<1024>(bb + ni * 128));
    asm volatile("s_waitcnt lgkmcnt(0)" ::: "memory");
    __builtin_amdgcn_sched_barrier(0);
#pragma unroll
    for (int ni = 0; ni < 4; ++ni) {
      acc[0][ni] = __builtin_amdgcn_mfma_f32_16x16x32_bf16(a0, b[ni], acc[0][ni], 0, 0, 0);
      acc[1][ni] = __builtin_amdgcn_mfma_f32_16x16x32_bf16(a1, b[ni], acc[1][ni], 0, 0, 0);
    }
    __builtin_amdgcn_sched_barrier(0);
    __builtin_amdgcn_s_barrier();
    bufc = bufc == 2 ? 0 : bufc + 1;
  }
#undef STG2

#pragma unroll
  for (int mi = 0; mi < 2; ++mi) {
#pragma unroll
    for (int j = 0; j < 4; ++j) {
      int grow = rt * 64 + wr * 32 + mi * 16 + kg * 4 + j;
      if (grow < cnt) {
        float* orow = obuf + (size_t)slot[e * T_TOK + grow] * H_DIM + nb + wc * 64 + fr;
#pragma unroll
        for (int ni = 0; ni < 4; ++ni)
          orow[ni * 16] = acc[mi][ni][j];
      }
    }
  }
}

// ---------------- reduce: out[t] = sum_k obuf[t*4+k] + obuf[4096+t] ----------------
__global__ void reduce_kernel(const float* __restrict__ obuf, float* __restrict__ out) {
  const int t = blockIdx.x;
  const int c = threadIdx.x;
  const f32x4* o4 = (const f32x4*)obuf;
  f32x4 s = o4[(size_t)(t * 4 + 0) * 256 + c];
  s += o4[(size_t)(t * 4 + 1) * 256 + c];
  s += o4[(size_t)(t * 4 + 2) * 256 + c];
  s += o4[(size_t)(t * 4 + 3) * 256 + c];
  s += o4[(size_t)(T_TOK * TOPK + t) * 256 + c];
  ((f32x4*)out)[(size_t)t * 256 + c] = s;
}

extern "C" void kernel_launch(void* const* d_in, const int* in_sizes, int n_in,
                              void* d_out, int out_size, void* d_ws, size_t ws_size,
                              hipStream_t stream) {
  const float* x   = (const float*)d_in[0];
  const float* gw  = (const float*)d_in[1];
  const float* wgu = (const float*)d_in[2];
  const float* wd  = (const float*)d_in[3];
  const float* sgu = (const float*)d_in[4];
  const float* sd  = (const float*)d_in[5];
  float* out = (float*)d_out;

  char* ws = (char*)d_ws;
  int*   counts = (int*)  (ws);                 // 1 KB
  int*   tok    = (int*)  (ws + 1024);          // 68 KB
  float* wtA    = (float*)(ws + 70656);         // 68 KB
  int*   slotA  = (int*)  (ws + 140288);        // 68 KB
  int*   topk_e = (int*)  (ws + 209920);        // 16 KB
  float* topk_w = (float*)(ws + 226304);        // 16 KB
  bf16*  xb     = (bf16*) (ws + 245760);        // 2 MB
  bf16*  hbuf   = (bf16*) (ws + 2342912);       // 5.25 MB
  bf16*  wguB   = (bf16*) (ws + 7585792);       // 32 MB  natural [E][1024][1024]
  bf16*  wdB    = (bf16*) (ws + 41140224);      // 16 MB  natural [E][512][1024]
  bf16*  sguB   = (bf16*) (ws + 57917440);      // 2 MB
  bf16*  sdB    = (bf16*) (ws + 60014592);      // 1 MB
  // obuf (20 MB fp32) aliases wguB: dead after gemm1, rewritten by prep next call.
  float* obuf   = (float*)(ws + 7585792);

  prep_kernel<<<13828, 256, 0, stream>>>(x, xb, wgu, wguB, wd, wdB, sgu, sguB, sd, sdB,
                                         gw, topk_e, topk_w, counts, tok, wtA, slotA);
  router_build_kernel<<<E_NUM, 256, 0, stream>>>(topk_e, topk_w, counts, tok, wtA, slotA);
  gemm1_kernel<<<dim3(8, 16, 17), 256, 0, stream>>>(xb, wguB, sguB, counts, tok, wtA, slotA, hbuf);
  gemm2_kernel<<<dim3(8, 16, 17), 256, 0, stream>>>(hbuf, wdB, sdB, counts, slotA, obuf);
  reduce_kernel<<<T_TOK, 256, 0, stream>>>(obuf, out);
}

// Round 15
// 92.566 us; speedup vs baseline: 1.3864x; 1.0527x over previous
//
#include <hip/hip_runtime.h>
#include <hip/hip_bf16.h>
#include <cstdint>

#define T_TOK 1024
#define H_DIM 1024
#define I_DIM 512
#define E_NUM 16
#define TOPK  4

typedef __bf16 bf16;
typedef __bf16 bf16x4 __attribute__((ext_vector_type(4)));
typedef __bf16 bf16x8 __attribute__((ext_vector_type(8)));
typedef float  f32x4  __attribute__((ext_vector_type(4)));

#define GLOAD16(g, l)                                                                   \
  __builtin_amdgcn_global_load_lds((const __attribute__((address_space(1))) void*)(g),  \
                                   (__attribute__((address_space(3))) void*)(l), 16, 0, 0)

__device__ __forceinline__ unsigned lds_addr(const bf16* p) {
  return (unsigned)(uintptr_t)(const __attribute__((address_space(3))) bf16*)p;
}

// hardware transpose read: lane l receives column (l&15) (4 bf16, rows j=0..3) of the
// 4x16 subtile whose 16 lanes supply base + (l&15)*8 bytes. OFF walks k-subtiles.
template <int OFF>
__device__ __forceinline__ bf16x4 tr_read(unsigned addr) {
  bf16x4 r;
  if constexpr (OFF == 0)
    asm volatile("ds_read_b64_tr_b16 %0, %1" : "=v"(r) : "v"(addr));
  else if constexpr (OFF == 512)
    asm volatile("ds_read_b64_tr_b16 %0, %1 offset:512" : "=v"(r) : "v"(addr));
  else
    asm volatile("ds_read_b64_tr_b16 %0, %1 offset:1024" : "=v"(r) : "v"(addr));
  return r;
}

__device__ __forceinline__ bf16x8 cat8(bf16x4 a, bf16x4 b) {
  return __builtin_shufflevector(a, b, 0, 1, 2, 3, 4, 5, 6, 7);
}

// ================= fused prep: grid-stride deep-MLP convert =================
// Convert task space (1 task = 256 threads x 8 float4-units = 8192 floats):
//   [0,2048)    wgu -> wguB
//   [2048,3072) wd  -> wdB
//   [3072,3200) sgu -> sguB
//   [3200,3264) sd  -> sdB
//   [3264,3392) x   -> xb
// blocks [0,1696) grid-stride 2 tasks each; [1696,1952) router_score; [1952,1956) init.
__global__ void prep_kernel(const float* __restrict__ x, bf16* __restrict__ xb,
                            const float* __restrict__ wgu, bf16* __restrict__ wguB,
                            const float* __restrict__ wd, bf16* __restrict__ wdB,
                            const float* __restrict__ sgu, bf16* __restrict__ sguB,
                            const float* __restrict__ sd, bf16* __restrict__ sdB,
                            const float* __restrict__ gw,
                            int* __restrict__ topk_e, float* __restrict__ topk_w,
                            int* __restrict__ counts, int* __restrict__ tok,
                            float* __restrict__ wt, int* __restrict__ slot) {
  const int b = blockIdx.x, tid = threadIdx.x;
  if (b < 1696) {
#pragma unroll
    for (int it = 0; it < 2; ++it) {
      const int task = b + it * 1696;
      const float* src; bf16* dst; int lt;
      if (task < 2048)      { src = wgu; dst = wguB; lt = task; }
      else if (task < 3072) { src = wd;  dst = wdB;  lt = task - 2048; }
      else if (task < 3200) { src = sgu; dst = sguB; lt = task - 3072; }
      else if (task < 3264) { src = sd;  dst = sdB;  lt = task - 3200; }
      else                  { src = x;   dst = xb;   lt = task - 3264; }
      const size_t base = (size_t)lt * 2048 + tid;   // float4-unit index, +q*256
      const float4* s4 = (const float4*)src;
      float4 f[8];
#pragma unroll
      for (int q = 0; q < 8; ++q) f[q] = s4[base + (size_t)q * 256];  // 8 loads in flight
      bf16x4* d4 = (bf16x4*)dst;
#pragma unroll
      for (int q = 0; q < 8; ++q) {
        bf16x4 p;
        p[0] = (bf16)f[q].x; p[1] = (bf16)f[q].y; p[2] = (bf16)f[q].z; p[3] = (bf16)f[q].w;
        d4[base + (size_t)q * 256] = p;
      }
    }
  } else if (b < 1952) {     // ---- router_score
    const int wave = tid >> 6, lane = tid & 63;
    const int t = (b - 1696) * 4 + wave;
    const float4* xr = (const float4*)(x + (size_t)t * H_DIM);
    float4 xv[4];
#pragma unroll
    for (int j = 0; j < 4; ++j) xv[j] = xr[lane + 64 * j];
    float p[E_NUM];
#pragma unroll
    for (int e = 0; e < E_NUM; ++e) {
      const float4* gr = (const float4*)(gw + (size_t)e * H_DIM);
      float s = 0.f;
#pragma unroll
      for (int j = 0; j < 4; ++j) {
        float4 g = gr[lane + 64 * j];
        s += xv[j].x * g.x + xv[j].y * g.y + xv[j].z * g.z + xv[j].w * g.w;
      }
      p[e] = s;
    }
#pragma unroll
    for (int off = 32; off > 0; off >>= 1) {
#pragma unroll
      for (int e = 0; e < E_NUM; ++e) p[e] += __shfl_xor(p[e], off);
    }
    float rem[E_NUM];
#pragma unroll
    for (int e = 0; e < E_NUM; ++e) rem[e] = 1.f / (1.f + __expf(-p[e]));
    float vals[TOPK]; int idx[TOPK];
#pragma unroll
    for (int k = 0; k < TOPK; ++k) {
      float m = rem[0]; int mi = 0;
#pragma unroll
      for (int e = 1; e < E_NUM; ++e) {
        if (rem[e] > m) { m = rem[e]; mi = e; }
      }
      vals[k] = m; idx[k] = mi;
#pragma unroll
      for (int e = 0; e < E_NUM; ++e) rem[e] = (e == mi) ? -1e30f : rem[e];
    }
    if (lane == 0) {
      float inv = 1.f / (vals[0] + vals[1] + vals[2] + vals[3]);
      int4 ids; ids.x = idx[0]; ids.y = idx[1]; ids.z = idx[2]; ids.w = idx[3];
      float4 w4; w4.x = vals[0]*inv; w4.y = vals[1]*inv; w4.z = vals[2]*inv; w4.w = vals[3]*inv;
      ((int4*)topk_e)[t] = ids;
      ((float4*)topk_w)[t] = w4;
    }
  } else {                   // ---- init shared-expert list
    const int i = (b - 1952) * 256 + tid;
    if (i == 0) counts[E_NUM] = T_TOK;
    tok [E_NUM * T_TOK + i] = i;
    wt  [E_NUM * T_TOK + i] = 1.0f;
    slot[E_NUM * T_TOK + i] = T_TOK * TOPK + i;
  }
}

// ---------------- router phase 2: per-expert list build via ballot prefix ----------------
__global__ void router_build_kernel(const int* __restrict__ topk_e, const float* __restrict__ topk_w,
                                    int* __restrict__ counts, int* __restrict__ tok,
                                    float* __restrict__ wt, int* __restrict__ slot) {
  const int e = blockIdx.x;
  const int tid = threadIdx.x, wave = tid >> 6, lane = tid & 63;
  __shared__ int wsum[4];
  int base = 0;
  for (int r = 0; r < 4; ++r) {
    int t = r * 256 + tid;
    int4 ids = ((const int4*)topk_e)[t];
    int match = -1;
    if (ids.x == e) match = 0;
    if (ids.y == e) match = 1;
    if (ids.z == e) match = 2;
    if (ids.w == e) match = 3;
    unsigned long long bm = __ballot(match >= 0);
    int prefix = __popcll(bm & ((1ull << lane) - 1ull));
    if (lane == 0) wsum[wave] = __popcll(bm);
    __syncthreads();
    int wbase = 0;
#pragma unroll
    for (int wv = 0; wv < 4; ++wv) wbase += (wv < wave) ? wsum[wv] : 0;
    int total = wsum[0] + wsum[1] + wsum[2] + wsum[3];
    if (match >= 0) {
      int pos = base + wbase + prefix;
      tok [e * T_TOK + pos] = t;
      wt  [e * T_TOK + pos] = topk_w[t * 4 + match];
      slot[e * T_TOK + pos] = t * 4 + match;
    }
    base += total;
    __syncthreads();
  }
  if (tid == 0) counts[e] = base;
}

// ---------------- GEMM1: Xb gathered @ Wgu(natural bf16) -> wt*swiglu -> h ----------------
__global__ __launch_bounds__(256, 4)
void gemm1_kernel(const bf16* __restrict__ xb, const bf16* __restrict__ wguB,
                  const bf16* __restrict__ sguB, const int* __restrict__ counts,
                  const int* __restrict__ tok, const float* __restrict__ wt,
                  const int* __restrict__ slot, bf16* __restrict__ hbuf) {
  const int e   = blockIdx.z;
  const int cnt = counts[e];
  const int rt  = blockIdx.y;
  if (rt * 64 >= cnt) return;
  const int nb = blockIdx.x * 64;
  const bf16* WB = (e < E_NUM) ? (wguB + (size_t)e * H_DIM * (2 * I_DIM)) : sguB;

  __shared__ __align__(16) bf16 sA[3][64 * 32];
  __shared__ __align__(16) bf16 sG[3][2048];
  __shared__ __align__(16) bf16 sU[3][2048];

  const int tid = threadIdx.x, wave = tid >> 6, lane = tid & 63;
  const int wr = wave >> 1, wc = wave & 1;
  const int fr = lane & 15, kg = lane >> 4;
  const int lr = lane >> 2, lk = (lane & 3) * 8;

  int ar = rt * 64 + wave * 16 + lr;
  int arc = ar < cnt ? ar : cnt - 1;
  const bf16* aS = xb + (size_t)tok[e * T_TOK + arc] * H_DIM + lk;
  const int aOff = wave * 512;

  const int k_off = 8 * wave + 4 * (lane >> 5) + ((lane & 7) >> 1);
  const int n_off = 16 * ((lane >> 3) & 3) + 8 * (lane & 1);
  const bf16* gS = WB + (size_t)k_off * (2 * I_DIM) + nb + n_off;
  const bf16* uS = WB + (size_t)k_off * (2 * I_DIM) + I_DIM + nb + n_off;
  const int wOff = wave * 512;

  f32x4 accg[2][2], accu[2][2];
#pragma unroll
  for (int i = 0; i < 2; ++i)
#pragma unroll
    for (int j = 0; j < 2; ++j) { accg[i][j] = f32x4{0,0,0,0}; accu[i][j] = f32x4{0,0,0,0}; }

#define STG1(t, bidx) do { size_t ko = (size_t)(t) * 32;    \
    GLOAD16(aS + ko, sA[bidx] + aOff);                      \
    GLOAD16(gS + ko * (2 * I_DIM), sG[bidx] + wOff);        \
    GLOAD16(uS + ko * (2 * I_DIM), sU[bidx] + wOff); } while (0)

  STG1(0, 0); STG1(1, 1);
  const int NT = H_DIM / 32;  // 32
  int bufc = 0;
  for (int t = 0; t < NT; ++t) {
    int bn = bufc + 2; bn = bn >= 3 ? bn - 3 : bn;
    if (t + 2 < NT) {
      STG1(t + 2, bn);
      asm volatile("s_waitcnt vmcnt(6)" ::: "memory");
    } else if (t + 1 < NT) {
      asm volatile("s_waitcnt vmcnt(3)" ::: "memory");
    } else {
      asm volatile("s_waitcnt vmcnt(0)" ::: "memory");
    }
    __builtin_amdgcn_s_barrier();
    __builtin_amdgcn_sched_barrier(0);
    const bf16* A = sA[bufc];
    bf16x8 a0 = *(const bf16x8*)(A + (wr * 32      + fr) * 32 + kg * 8);
    bf16x8 a1 = *(const bf16x8*)(A + (wr * 32 + 16 + fr) * 32 + kg * 8);
    unsigned gb = lds_addr(sG[bufc]) + (unsigned)((lane >> 4) << 10) + (unsigned)((lane & 15) << 3);
    unsigned ub = lds_addr(sU[bufc]) + (unsigned)((lane >> 4) << 10) + (unsigned)((lane & 15) << 3);
    unsigned nb0 = (unsigned)(wc * 256), nb1 = nb0 + 128;
    bf16x8 g0 = cat8(tr_read<0>(gb + nb0), tr_read<512>(gb + nb0));
    bf16x8 g1 = cat8(tr_read<0>(gb + nb1), tr_read<512>(gb + nb1));
    bf16x8 u0 = cat8(tr_read<0>(ub + nb0), tr_read<512>(ub + nb0));
    bf16x8 u1 = cat8(tr_read<0>(ub + nb1), tr_read<512>(ub + nb1));
    asm volatile("s_waitcnt lgkmcnt(0)" ::: "memory");
    __builtin_amdgcn_sched_barrier(0);
    accg[0][0] = __builtin_amdgcn_mfma_f32_16x16x32_bf16(a0, g0, accg[0][0], 0, 0, 0);
    accg[0][1] = __builtin_amdgcn_mfma_f32_16x16x32_bf16(a0, g1, accg[0][1], 0, 0, 0);
    accg[1][0] = __builtin_amdgcn_mfma_f32_16x16x32_bf16(a1, g0, accg[1][0], 0, 0, 0);
    accg[1][1] = __builtin_amdgcn_mfma_f32_16x16x32_bf16(a1, g1, accg[1][1], 0, 0, 0);
    accu[0][0] = __builtin_amdgcn_mfma_f32_16x16x32_bf16(a0, u0, accu[0][0], 0, 0, 0);
    accu[0][1] = __builtin_amdgcn_mfma_f32_16x16x32_bf16(a0, u1, accu[0][1], 0, 0, 0);
    accu[1][0] = __builtin_amdgcn_mfma_f32_16x16x32_bf16(a1, u0, accu[1][0], 0, 0, 0);
    accu[1][1] = __builtin_amdgcn_mfma_f32_16x16x32_bf16(a1, u1, accu[1][1], 0, 0, 0);
    __builtin_amdgcn_sched_barrier(0);
    __builtin_amdgcn_s_barrier();
    bufc = bufc == 2 ? 0 : bufc + 1;
  }
#undef STG1

#pragma unroll
  for (int mi = 0; mi < 2; ++mi) {
#pragma unroll
    for (int j = 0; j < 4; ++j) {
      int grow = rt * 64 + wr * 32 + mi * 16 + kg * 4 + j;
      if (grow < cnt) {
        bf16* hr = hbuf + (size_t)slot[e * T_TOK + grow] * I_DIM;
        float w = wt[e * T_TOK + grow];
#pragma unroll
        for (int ni = 0; ni < 2; ++ni) {
          float g = accg[mi][ni][j], u = accu[mi][ni][j];
          float h = w * (g / (1.f + __expf(-g))) * u;
          hr[nb + wc * 32 + ni * 16 + fr] = (bf16)h;
        }
      }
    }
  }
}

// ---------------- GEMM2: h gathered @ Wd(natural bf16) -> plain stores into obuf ----------------
__global__ __launch_bounds__(256, 4)
void gemm2_kernel(const bf16* __restrict__ hbuf, const bf16* __restrict__ wdB,
                  const bf16* __restrict__ sdB, const int* __restrict__ counts,
                  const int* __restrict__ slot, float* __restrict__ obuf) {
  const int e   = blockIdx.z;
  const int cnt = counts[e];
  const int rt  = blockIdx.y;
  if (rt * 64 >= cnt) return;
  const int nb = blockIdx.x * 128;
  const bf16* WB = (e < E_NUM) ? (wdB + (size_t)e * I_DIM * H_DIM) : sdB;

  __shared__ __align__(16) bf16 sA[3][64 * 32];
  __shared__ __align__(16) bf16 sB[3][4096];

  const int tid = threadIdx.x, wave = tid >> 6, lane = tid & 63;
  const int wr = wave >> 1, wc = wave & 1;
  const int fr = lane & 15, kg = lane >> 4;
  const int lr = lane >> 2, lk = (lane & 3) * 8;

  int ar = rt * 64 + wave * 16 + lr;
  int arc = ar < cnt ? ar : cnt - 1;
  const bf16* aS = hbuf + (size_t)slot[e * T_TOK + arc] * I_DIM + lk;
  const int aOff = wave * 512;

  const int j2 = (lane & 7) >> 1, h2 = lane & 1, nblk2 = lane >> 3;
  const int n2 = nb + nblk2 * 16 + 8 * h2;
  const bf16* bS0 = WB + (size_t)((wave * 2 + 0) * 4 + j2) * H_DIM + n2;
  const bf16* bS1 = WB + (size_t)((wave * 2 + 1) * 4 + j2) * H_DIM + n2;
  const int bOff0 = wave * 1024;
  const int bOff1 = bOff0 + 512;

  f32x4 acc[2][4];
#pragma unroll
  for (int i = 0; i < 2; ++i)
#pragma unroll
    for (int j = 0; j < 4; ++j) acc[i][j] = f32x4{0,0,0,0};

#define STG2(t, bidx) do { size_t ko = (size_t)(t) * 32;    \
    GLOAD16(aS + ko, sA[bidx] + aOff);                      \
    GLOAD16(bS0 + ko * H_DIM, sB[bidx] + bOff0);            \
    GLOAD16(bS1 + ko * H_DIM, sB[bidx] + bOff1); } while (0)

  STG2(0, 0); STG2(1, 1);
  const int NT = I_DIM / 32;  // 16
  int bufc = 0;
  for (int t = 0; t < NT; ++t) {
    int bn = bufc + 2; bn = bn >= 3 ? bn - 3 : bn;
    if (t + 2 < NT) {
      STG2(t + 2, bn);
      asm volatile("s_waitcnt vmcnt(6)" ::: "memory");
    } else if (t + 1 < NT) {
      asm volatile("s_waitcnt vmcnt(3)" ::: "memory");
    } else {
      asm volatile("s_waitcnt vmcnt(0)" ::: "memory");
    }
    __builtin_amdgcn_s_barrier();
    __builtin_amdgcn_sched_barrier(0);
    const bf16* A = sA[bufc];
    bf16x8 a0 = *(const bf16x8*)(A + (wr * 32      + fr) * 32 + kg * 8);
    bf16x8 a1 = *(const bf16x8*)(A + (wr * 32 + 16 + fr) * 32 + kg * 8);
    unsigned bb = lds_addr(sB[bufc]) + (unsigned)((lane >> 4) << 11) + (unsigned)((lane & 15) << 3)
                + (unsigned)(wc * 512);
    bf16x8 b[4];
#pragma unroll
    for (int ni = 0; ni < 4; ++ni)
      b[ni] = cat8(tr_read<0>(bb + ni * 128), tr_read<1024>(bb + ni * 128));
    asm volatile("s_waitcnt lgkmcnt(0)" ::: "memory");
    __builtin_amdgcn_sched_barrier(0);
#pragma unroll
    for (int ni = 0; ni < 4; ++ni) {
      acc[0][ni] = __builtin_amdgcn_mfma_f32_16x16x32_bf16(a0, b[ni], acc[0][ni], 0, 0, 0);
      acc[1][ni] = __builtin_amdgcn_mfma_f32_16x16x32_bf16(a1, b[ni], acc[1][ni], 0, 0, 0);
    }
    __builtin_amdgcn_sched_barrier(0);
    __builtin_amdgcn_s_barrier();
    bufc = bufc == 2 ? 0 : bufc + 1;
  }
#undef STG2

#pragma unroll
  for (int mi = 0; mi < 2; ++mi) {
#pragma unroll
    for (int j = 0; j < 4; ++j) {
      int grow = rt * 64 + wr * 32 + mi * 16 + kg * 4 + j;
      if (grow < cnt) {
        float* orow = obuf + (size_t)slot[e * T_TOK + grow] * H_DIM + nb + wc * 64 + fr;
#pragma unroll
        for (int ni = 0; ni < 4; ++ni)
          orow[ni * 16] = acc[mi][ni][j];
      }
    }
  }
}

// ---------------- reduce: out[t] = sum_k obuf[t*4+k] + obuf[4096+t] ----------------
__global__ void reduce_kernel(const float* __restrict__ obuf, float* __restrict__ out) {
  const int t = blockIdx.x;
  const int c = threadIdx.x;
  const f32x4* o4 = (const f32x4*)obuf;
  f32x4 s = o4[(size_t)(t * 4 + 0) * 256 + c];
  s += o4[(size_t)(t * 4 + 1) * 256 + c];
  s += o4[(size_t)(t * 4 + 2) * 256 + c];
  s += o4[(size_t)(t * 4 + 3) * 256 + c];
  s += o4[(size_t)(T_TOK * TOPK + t) * 256 + c];
  ((f32x4*)out)[(size_t)t * 256 + c] = s;
}

extern "C" void kernel_launch(void* const* d_in, const int* in_sizes, int n_in,
                              void* d_out, int out_size, void* d_ws, size_t ws_size,
                              hipStream_t stream) {
  const float* x   = (const float*)d_in[0];
  const float* gw  = (const float*)d_in[1];
  const float* wgu = (const float*)d_in[2];
  const float* wd  = (const float*)d_in[3];
  const float* sgu = (const float*)d_in[4];
  const float* sd  = (const float*)d_in[5];
  float* out = (float*)d_out;

  char* ws = (char*)d_ws;
  int*   counts = (int*)  (ws);                 // 1 KB
  int*   tok    = (int*)  (ws + 1024);          // 68 KB
  float* wtA    = (float*)(ws + 70656);         // 68 KB
  int*   slotA  = (int*)  (ws + 140288);        // 68 KB
  int*   topk_e = (int*)  (ws + 209920);        // 16 KB
  float* topk_w = (float*)(ws + 226304);        // 16 KB
  bf16*  xb     = (bf16*) (ws + 245760);        // 2 MB
  bf16*  hbuf   = (bf16*) (ws + 2342912);       // 5.25 MB
  bf16*  wguB   = (bf16*) (ws + 7585792);       // 32 MB  natural [E][1024][1024]
  bf16*  wdB    = (bf16*) (ws + 41140224);      // 16 MB  natural [E][512][1024]
  bf16*  sguB   = (bf16*) (ws + 57917440);      // 2 MB
  bf16*  sdB    = (bf16*) (ws + 60014592);      // 1 MB
  // obuf (20 MB fp32) aliases wguB: dead after gemm1, rewritten by prep next call.
  float* obuf   = (float*)(ws + 7585792);

  prep_kernel<<<1956, 256, 0, stream>>>(x, xb, wgu, wguB, wd, wdB, sgu, sguB, sd, sdB,
                                        gw, topk_e, topk_w, counts, tok, wtA, slotA);
  router_build_kernel<<<E_NUM, 256, 0, stream>>>(topk_e, topk_w, counts, tok, wtA, slotA);
  gemm1_kernel<<<dim3(8, 16, 17), 256, 0, stream>>>(xb, wguB, sguB, counts, tok, wtA, slotA, hbuf);
  gemm2_kernel<<<dim3(8, 16, 17), 256, 0, stream>>>(hbuf, wdB, sdB, counts, slotA, obuf);
  reduce_kernel<<<T_TOK, 256, 0, stream>>>(obuf, out);
}

// Round 16
// 87.644 us; speedup vs baseline: 1.4642x; 1.0562x over previous
//
#include <hip/hip_runtime.h>
#include <hip/hip_bf16.h>
#include <cstdint>

#define T_TOK 1024
#define H_DIM 1024
#define I_DIM 512
#define E_NUM 16
#define TOPK  4

typedef __bf16 bf16;
typedef __bf16 bf16x4 __attribute__((ext_vector_type(4)));
typedef __bf16 bf16x8 __attribute__((ext_vector_type(8)));
typedef float  f32x4  __attribute__((ext_vector_type(4)));

#define GLOAD16(g, l)                                                                   \
  __builtin_amdgcn_global_load_lds((const __attribute__((address_space(1))) void*)(g),  \
                                   (__attribute__((address_space(3))) void*)(l), 16, 0, 0)

__device__ __forceinline__ unsigned lds_addr(const bf16* p) {
  return (unsigned)(uintptr_t)(const __attribute__((address_space(3))) bf16*)p;
}

// hardware transpose read: lane l receives column (l&15) (4 bf16, rows j=0..3) of the
// 4x16 subtile whose 16 lanes supply base + (l&15)*8 bytes. OFF walks k-subtiles.
template <int OFF>
__device__ __forceinline__ bf16x4 tr_read(unsigned addr) {
  bf16x4 r;
  if constexpr (OFF == 0)
    asm volatile("ds_read_b64_tr_b16 %0, %1" : "=v"(r) : "v"(addr));
  else if constexpr (OFF == 512)
    asm volatile("ds_read_b64_tr_b16 %0, %1 offset:512" : "=v"(r) : "v"(addr));
  else
    asm volatile("ds_read_b64_tr_b16 %0, %1 offset:1024" : "=v"(r) : "v"(addr));
  return r;
}

__device__ __forceinline__ bf16x8 cat8(bf16x4 a, bf16x4 b) {
  return __builtin_shufflevector(a, b, 0, 1, 2, 3, 4, 5, 6, 7);
}

// one convert task: 256 threads x 8 float4-units (8192 floats), 8 loads in flight
__device__ __forceinline__ void conv_task(const float* __restrict__ src,
                                          bf16* __restrict__ dst, int lt, int tid) {
  const size_t base = (size_t)lt * 2048 + tid;
  const float4* s4 = (const float4*)src;
  float4 f[8];
#pragma unroll
  for (int q = 0; q < 8; ++q) f[q] = s4[base + (size_t)q * 256];
  bf16x4* d4 = (bf16x4*)dst;
#pragma unroll
  for (int q = 0; q < 8; ++q) {
    bf16x4 p;
    p[0] = (bf16)f[q].x; p[1] = (bf16)f[q].y; p[2] = (bf16)f[q].z; p[3] = (bf16)f[q].w;
    d4[base + (size_t)q * 256] = p;
  }
}

// ================= prep: wgu/sgu/x convert + router_score + init =================
// task space: [0,2048) wgu; [2048,2176) sgu; [2176,2304) x.
// blocks [0,1152) grid-stride 2 tasks; [1152,1408) router_score; [1408,1412) init.
__global__ void prep_kernel(const float* __restrict__ x, bf16* __restrict__ xb,
                            const float* __restrict__ wgu, bf16* __restrict__ wguB,
                            const float* __restrict__ sgu, bf16* __restrict__ sguB,
                            const float* __restrict__ gw,
                            int* __restrict__ topk_e, float* __restrict__ topk_w,
                            int* __restrict__ counts, int* __restrict__ tok,
                            float* __restrict__ wt, int* __restrict__ slot) {
  const int b = blockIdx.x, tid = threadIdx.x;
  if (b < 1152) {
#pragma unroll
    for (int it = 0; it < 2; ++it) {
      const int task = b + it * 1152;
      if (task < 2048)      conv_task(wgu, wguB, task, tid);
      else if (task < 2176) conv_task(sgu, sguB, task - 2048, tid);
      else                  conv_task(x, xb, task - 2176, tid);
    }
  } else if (b < 1408) {     // ---- router_score
    const int wave = tid >> 6, lane = tid & 63;
    const int t = (b - 1152) * 4 + wave;
    const float4* xr = (const float4*)(x + (size_t)t * H_DIM);
    float4 xv[4];
#pragma unroll
    for (int j = 0; j < 4; ++j) xv[j] = xr[lane + 64 * j];
    float p[E_NUM];
#pragma unroll
    for (int e = 0; e < E_NUM; ++e) {
      const float4* gr = (const float4*)(gw + (size_t)e * H_DIM);
      float s = 0.f;
#pragma unroll
      for (int j = 0; j < 4; ++j) {
        float4 g = gr[lane + 64 * j];
        s += xv[j].x * g.x + xv[j].y * g.y + xv[j].z * g.z + xv[j].w * g.w;
      }
      p[e] = s;
    }
#pragma unroll
    for (int off = 32; off > 0; off >>= 1) {
#pragma unroll
      for (int e = 0; e < E_NUM; ++e) p[e] += __shfl_xor(p[e], off);
    }
    float rem[E_NUM];
#pragma unroll
    for (int e = 0; e < E_NUM; ++e) rem[e] = 1.f / (1.f + __expf(-p[e]));
    float vals[TOPK]; int idx[TOPK];
#pragma unroll
    for (int k = 0; k < TOPK; ++k) {
      float m = rem[0]; int mi = 0;
#pragma unroll
      for (int e = 1; e < E_NUM; ++e) {
        if (rem[e] > m) { m = rem[e]; mi = e; }
      }
      vals[k] = m; idx[k] = mi;
#pragma unroll
      for (int e = 0; e < E_NUM; ++e) rem[e] = (e == mi) ? -1e30f : rem[e];
    }
    if (lane == 0) {
      float inv = 1.f / (vals[0] + vals[1] + vals[2] + vals[3]);
      int4 ids; ids.x = idx[0]; ids.y = idx[1]; ids.z = idx[2]; ids.w = idx[3];
      float4 w4; w4.x = vals[0]*inv; w4.y = vals[1]*inv; w4.z = vals[2]*inv; w4.w = vals[3]*inv;
      ((int4*)topk_e)[t] = ids;
      ((float4*)topk_w)[t] = w4;
    }
  } else {                   // ---- init shared-expert list
    const int i = (b - 1408) * 256 + tid;
    if (i == 0) counts[E_NUM] = T_TOK;
    tok [E_NUM * T_TOK + i] = i;
    wt  [E_NUM * T_TOK + i] = 1.0f;
    slot[E_NUM * T_TOK + i] = T_TOK * TOPK + i;
  }
}

// ---------------- router phase 2: per-expert list build via ballot prefix ----------------
__global__ void router_build_kernel(const int* __restrict__ topk_e, const float* __restrict__ topk_w,
                                    int* __restrict__ counts, int* __restrict__ tok,
                                    float* __restrict__ wt, int* __restrict__ slot) {
  const int e = blockIdx.x;
  const int tid = threadIdx.x, wave = tid >> 6, lane = tid & 63;
  __shared__ int wsum[4];
  int base = 0;
  for (int r = 0; r < 4; ++r) {
    int t = r * 256 + tid;
    int4 ids = ((const int4*)topk_e)[t];
    int match = -1;
    if (ids.x == e) match = 0;
    if (ids.y == e) match = 1;
    if (ids.z == e) match = 2;
    if (ids.w == e) match = 3;
    unsigned long long bm = __ballot(match >= 0);
    int prefix = __popcll(bm & ((1ull << lane) - 1ull));
    if (lane == 0) wsum[wave] = __popcll(bm);
    __syncthreads();
    int wbase = 0;
#pragma unroll
    for (int wv = 0; wv < 4; ++wv) wbase += (wv < wave) ? wsum[wv] : 0;
    int total = wsum[0] + wsum[1] + wsum[2] + wsum[3];
    if (match >= 0) {
      int pos = base + wbase + prefix;
      tok [e * T_TOK + pos] = t;
      wt  [e * T_TOK + pos] = topk_w[t * 4 + match];
      slot[e * T_TOK + pos] = t * 4 + match;
    }
    base += total;
    __syncthreads();
  }
  if (tid == 0) counts[e] = base;
}

// ---------------- GEMM1 (z<17) + wd/sd convert blocks (z>=17) ----------------
// gemm1: Xb gathered @ Wgu(natural bf16) -> wt*swiglu -> h. Convert blocks stream
// wd/sd fp32->bf16 in gemm1's bandwidth shadow (wd only needed by gemm2).
__global__ __launch_bounds__(256, 4)
void gemm1_kernel(const bf16* __restrict__ xb, const bf16* __restrict__ wguB,
                  const bf16* __restrict__ sguB, const int* __restrict__ counts,
                  const int* __restrict__ tok, const float* __restrict__ wt,
                  const int* __restrict__ slot, bf16* __restrict__ hbuf,
                  const float* __restrict__ wdF, bf16* __restrict__ wdBo,
                  const float* __restrict__ sdF, bf16* __restrict__ sdBo) {
  const int tid = threadIdx.x;
  const int e = blockIdx.z;
  if (e >= 17) {  // ---- convert role: wd (1024 tasks) + sd (64 tasks)
    const int cid = (e - 17) * 128 + blockIdx.y * 8 + blockIdx.x;
    if (cid < 1024)      conv_task(wdF, wdBo, cid, tid);
    else if (cid < 1088) conv_task(sdF, sdBo, cid - 1024, tid);
    return;
  }
  const int cnt = counts[e];
  const int rt  = blockIdx.y;
  if (rt * 64 >= cnt) return;
  const int nb = blockIdx.x * 64;
  const bf16* WB = (e < E_NUM) ? (wguB + (size_t)e * H_DIM * (2 * I_DIM)) : sguB;

  __shared__ __align__(16) bf16 sA[3][64 * 32];
  __shared__ __align__(16) bf16 sG[3][2048];
  __shared__ __align__(16) bf16 sU[3][2048];

  const int wave = tid >> 6, lane = tid & 63;
  const int wr = wave >> 1, wc = wave & 1;
  const int fr = lane & 15, kg = lane >> 4;
  const int lr = lane >> 2, lk = (lane & 3) * 8;

  int ar = rt * 64 + wave * 16 + lr;
  int arc = ar < cnt ? ar : cnt - 1;
  const bf16* aS = xb + (size_t)tok[e * T_TOK + arc] * H_DIM + lk;
  const int aOff = wave * 512;

  const int k_off = 8 * wave + 4 * (lane >> 5) + ((lane & 7) >> 1);
  const int n_off = 16 * ((lane >> 3) & 3) + 8 * (lane & 1);
  const bf16* gS = WB + (size_t)k_off * (2 * I_DIM) + nb + n_off;
  const bf16* uS = WB + (size_t)k_off * (2 * I_DIM) + I_DIM + nb + n_off;
  const int wOff = wave * 512;

  f32x4 accg[2][2], accu[2][2];
#pragma unroll
  for (int i = 0; i < 2; ++i)
#pragma unroll
    for (int j = 0; j < 2; ++j) { accg[i][j] = f32x4{0,0,0,0}; accu[i][j] = f32x4{0,0,0,0}; }

#define STG1(t, bidx) do { size_t ko = (size_t)(t) * 32;    \
    GLOAD16(aS + ko, sA[bidx] + aOff);                      \
    GLOAD16(gS + ko * (2 * I_DIM), sG[bidx] + wOff);        \
    GLOAD16(uS + ko * (2 * I_DIM), sU[bidx] + wOff); } while (0)

  STG1(0, 0); STG1(1, 1);
  const int NT = H_DIM / 32;  // 32
  int bufc = 0;
  for (int t = 0; t < NT; ++t) {
    int bn = bufc + 2; bn = bn >= 3 ? bn - 3 : bn;
    if (t + 2 < NT) {
      STG1(t + 2, bn);
      asm volatile("s_waitcnt vmcnt(6)" ::: "memory");
    } else if (t + 1 < NT) {
      asm volatile("s_waitcnt vmcnt(3)" ::: "memory");
    } else {
      asm volatile("s_waitcnt vmcnt(0)" ::: "memory");
    }
    __builtin_amdgcn_s_barrier();
    __builtin_amdgcn_sched_barrier(0);
    const bf16* A = sA[bufc];
    bf16x8 a0 = *(const bf16x8*)(A + (wr * 32      + fr) * 32 + kg * 8);
    bf16x8 a1 = *(const bf16x8*)(A + (wr * 32 + 16 + fr) * 32 + kg * 8);
    unsigned gb = lds_addr(sG[bufc]) + (unsigned)((lane >> 4) << 10) + (unsigned)((lane & 15) << 3);
    unsigned ub = lds_addr(sU[bufc]) + (unsigned)((lane >> 4) << 10) + (unsigned)((lane & 15) << 3);
    unsigned nb0 = (unsigned)(wc * 256), nb1 = nb0 + 128;
    bf16x8 g0 = cat8(tr_read<0>(gb + nb0), tr_read<512>(gb + nb0));
    bf16x8 g1 = cat8(tr_read<0>(gb + nb1), tr_read<512>(gb + nb1));
    bf16x8 u0 = cat8(tr_read<0>(ub + nb0), tr_read<512>(ub + nb0));
    bf16x8 u1 = cat8(tr_read<0>(ub + nb1), tr_read<512>(ub + nb1));
    asm volatile("s_waitcnt lgkmcnt(0)" ::: "memory");
    __builtin_amdgcn_sched_barrier(0);
    accg[0][0] = __builtin_amdgcn_mfma_f32_16x16x32_bf16(a0, g0, accg[0][0], 0, 0, 0);
    accg[0][1] = __builtin_amdgcn_mfma_f32_16x16x32_bf16(a0, g1, accg[0][1], 0, 0, 0);
    accg[1][0] = __builtin_amdgcn_mfma_f32_16x16x32_bf16(a1, g0, accg[1][0], 0, 0, 0);
    accg[1][1] = __builtin_amdgcn_mfma_f32_16x16x32_bf16(a1, g1, accg[1][1], 0, 0, 0);
    accu[0][0] = __builtin_amdgcn_mfma_f32_16x16x32_bf16(a0, u0, accu[0][0], 0, 0, 0);
    accu[0][1] = __builtin_amdgcn_mfma_f32_16x16x32_bf16(a0, u1, accu[0][1], 0, 0, 0);
    accu[1][0] = __builtin_amdgcn_mfma_f32_16x16x32_bf16(a1, u0, accu[1][0], 0, 0, 0);
    accu[1][1] = __builtin_amdgcn_mfma_f32_16x16x32_bf16(a1, u1, accu[1][1], 0, 0, 0);
    __builtin_amdgcn_sched_barrier(0);
    __builtin_amdgcn_s_barrier();
    bufc = bufc == 2 ? 0 : bufc + 1;
  }
#undef STG1

#pragma unroll
  for (int mi = 0; mi < 2; ++mi) {
#pragma unroll
    for (int j = 0; j < 4; ++j) {
      int grow = rt * 64 + wr * 32 + mi * 16 + kg * 4 + j;
      if (grow < cnt) {
        bf16* hr = hbuf + (size_t)slot[e * T_TOK + grow] * I_DIM;
        float w = wt[e * T_TOK + grow];
#pragma unroll
        for (int ni = 0; ni < 2; ++ni) {
          float g = accg[mi][ni][j], u = accu[mi][ni][j];
          float h = w * (g / (1.f + __expf(-g))) * u;
          hr[nb + wc * 32 + ni * 16 + fr] = (bf16)h;
        }
      }
    }
  }
}

// ---------------- GEMM2: h gathered @ Wd(natural bf16) -> plain stores into obuf ----------------
__global__ __launch_bounds__(256, 4)
void gemm2_kernel(const bf16* __restrict__ hbuf, const bf16* __restrict__ wdB,
                  const bf16* __restrict__ sdB, const int* __restrict__ counts,
                  const int* __restrict__ slot, float* __restrict__ obuf) {
  const int e   = blockIdx.z;
  const int cnt = counts[e];
  const int rt  = blockIdx.y;
  if (rt * 64 >= cnt) return;
  const int nb = blockIdx.x * 128;
  const bf16* WB = (e < E_NUM) ? (wdB + (size_t)e * I_DIM * H_DIM) : sdB;

  __shared__ __align__(16) bf16 sA[3][64 * 32];
  __shared__ __align__(16) bf16 sB[3][4096];

  const int tid = threadIdx.x, wave = tid >> 6, lane = tid & 63;
  const int wr = wave >> 1, wc = wave & 1;
  const int fr = lane & 15, kg = lane >> 4;
  const int lr = lane >> 2, lk = (lane & 3) * 8;

  int ar = rt * 64 + wave * 16 + lr;
  int arc = ar < cnt ? ar : cnt - 1;
  const bf16* aS = hbuf + (size_t)slot[e * T_TOK + arc] * I_DIM + lk;
  const int aOff = wave * 512;

  const int j2 = (lane & 7) >> 1, h2 = lane & 1, nblk2 = lane >> 3;
  const int n2 = nb + nblk2 * 16 + 8 * h2;
  const bf16* bS0 = WB + (size_t)((wave * 2 + 0) * 4 + j2) * H_DIM + n2;
  const bf16* bS1 = WB + (size_t)((wave * 2 + 1) * 4 + j2) * H_DIM + n2;
  const int bOff0 = wave * 1024;
  const int bOff1 = bOff0 + 512;

  f32x4 acc[2][4];
#pragma unroll
  for (int i = 0; i < 2; ++i)
#pragma unroll
    for (int j = 0; j < 4; ++j) acc[i][j] = f32x4{0,0,0,0};

#define STG2(t, bidx) do { size_t ko = (size_t)(t) * 32;    \
    GLOAD16(aS + ko, sA[bidx] + aOff);                      \
    GLOAD16(bS0 + ko * H_DIM, sB[bidx] + bOff0);            \
    GLOAD16(bS1 + ko * H_DIM, sB[bidx] + bOff1); } while (0)

  STG2(0, 0); STG2(1, 1);
  const int NT = I_DIM / 32;  // 16
  int bufc = 0;
  for (int t = 0; t < NT; ++t) {
    int bn = bufc + 2; bn = bn >= 3 ? bn - 3 : bn;
    if (t + 2 < NT) {
      STG2(t + 2, bn);
      asm volatile("s_waitcnt vmcnt(6)" ::: "memory");
    } else if (t + 1 < NT) {
      asm volatile("s_waitcnt vmcnt(3)" ::: "memory");
    } else {
      asm volatile("s_waitcnt vmcnt(0)" ::: "memory");
    }
    __builtin_amdgcn_s_barrier();
    __builtin_amdgcn_sched_barrier(0);
    const bf16* A = sA[bufc];
    bf16x8 a0 = *(const bf16x8*)(A + (wr * 32      + fr) * 32 + kg * 8);
    bf16x8 a1 = *(const bf16x8*)(A + (wr * 32 + 16 + fr) * 32 + kg * 8);
    unsigned bb = lds_addr(sB[bufc]) + (unsigned)((lane >> 4) << 11) + (unsigned)((lane & 15) << 3)
                + (unsigned)(wc * 512);
    bf16x8 b[4];
#pragma unroll
    for (int ni = 0; ni < 4; ++ni)
      b[ni] = cat8(tr_read<0>(bb + ni * 128), tr_read<1024>(bb + ni * 128));
    asm volatile("s_waitcnt lgkmcnt(0)" ::: "memory");
    __builtin_amdgcn_sched_barrier(0);
#pragma unroll
    for (int ni = 0; ni < 4; ++ni) {
      acc[0][ni] = __builtin_amdgcn_mfma_f32_16x16x32_bf16(a0, b[ni], acc[0][ni], 0, 0, 0);
      acc[1][ni] = __builtin_amdgcn_mfma_f32_16x16x32_bf16(a1, b[ni], acc[1][ni], 0, 0, 0);
    }
    __builtin_amdgcn_sched_barrier(0);
    __builtin_amdgcn_s_barrier();
    bufc = bufc == 2 ? 0 : bufc + 1;
  }
#undef STG2

#pragma unroll
  for (int mi = 0; mi < 2; ++mi) {
#pragma unroll
    for (int j = 0; j < 4; ++j) {
      int grow = rt * 64 + wr * 32 + mi * 16 + kg * 4 + j;
      if (grow < cnt) {
        float* orow = obuf + (size_t)slot[e * T_TOK + grow] * H_DIM + nb + wc * 64 + fr;
#pragma unroll
        for (int ni = 0; ni < 4; ++ni)
          orow[ni * 16] = acc[mi][ni][j];
      }
    }
  }
}

// ---------------- reduce: out[t] = sum_k obuf[t*4+k] + obuf[4096+t] ----------------
__global__ void reduce_kernel(const float* __restrict__ obuf, float* __restrict__ out) {
  const int t = blockIdx.x;
  const int c = threadIdx.x;
  const f32x4* o4 = (const f32x4*)obuf;
  f32x4 s = o4[(size_t)(t * 4 + 0) * 256 + c];
  s += o4[(size_t)(t * 4 + 1) * 256 + c];
  s += o4[(size_t)(t * 4 + 2) * 256 + c];
  s += o4[(size_t)(t * 4 + 3) * 256 + c];
  s += o4[(size_t)(T_TOK * TOPK + t) * 256 + c];
  ((f32x4*)out)[(size_t)t * 256 + c] = s;
}

extern "C" void kernel_launch(void* const* d_in, const int* in_sizes, int n_in,
                              void* d_out, int out_size, void* d_ws, size_t ws_size,
                              hipStream_t stream) {
  const float* x   = (const float*)d_in[0];
  const float* gw  = (const float*)d_in[1];
  const float* wgu = (const float*)d_in[2];
  const float* wd  = (const float*)d_in[3];
  const float* sgu = (const float*)d_in[4];
  const float* sd  = (const float*)d_in[5];
  float* out = (float*)d_out;

  char* ws = (char*)d_ws;
  int*   counts = (int*)  (ws);                 // 1 KB
  int*   tok    = (int*)  (ws + 1024);          // 68 KB
  float* wtA    = (float*)(ws + 70656);         // 68 KB
  int*   slotA  = (int*)  (ws + 140288);        // 68 KB
  int*   topk_e = (int*)  (ws + 209920);        // 16 KB
  float* topk_w = (float*)(ws + 226304);        // 16 KB
  bf16*  xb     = (bf16*) (ws + 245760);        // 2 MB
  bf16*  hbuf   = (bf16*) (ws + 2342912);       // 5.25 MB
  bf16*  wguB   = (bf16*) (ws + 7585792);       // 32 MB  natural [E][1024][1024]
  bf16*  wdB    = (bf16*) (ws + 41140224);      // 16 MB  natural [E][512][1024]
  bf16*  sguB   = (bf16*) (ws + 57917440);      // 2 MB
  bf16*  sdB    = (bf16*) (ws + 60014592);      // 1 MB
  // obuf (20 MB fp32) aliases wguB: dead after gemm1, rewritten by prep next call.
  float* obuf   = (float*)(ws + 7585792);

  prep_kernel<<<1412, 256, 0, stream>>>(x, xb, wgu, wguB, sgu, sguB,
                                        gw, topk_e, topk_w, counts, tok, wtA, slotA);
  router_build_kernel<<<E_NUM, 256, 0, stream>>>(topk_e, topk_w, counts, tok, wtA, slotA);
  gemm1_kernel<<<dim3(8, 16, 26), 256, 0, stream>>>(xb, wguB, sguB, counts, tok, wtA, slotA,
                                                    hbuf, wd, wdB, sd, sdB);
  gemm2_kernel<<<dim3(8, 16, 17), 256, 0, stream>>>(hbuf, wdB, sdB, counts, slotA, obuf);
  reduce_kernel<<<T_TOK, 256, 0, stream>>>(obuf, out);
}

// Round 17
// 85.867 us; speedup vs baseline: 1.4945x; 1.0207x over previous
//
#include <hip/hip_runtime.h>
#include <hip/hip_bf16.h>
#include <cstdint>

#define T_TOK 1024
#define H_DIM 1024
#define I_DIM 512
#define E_NUM 16
#define TOPK  4

typedef __bf16 bf16;
typedef __bf16 bf16x4 __attribute__((ext_vector_type(4)));
typedef __bf16 bf16x8 __attribute__((ext_vector_type(8)));
typedef float  f32x4  __attribute__((ext_vector_type(4)));

#define GLOAD16(g, l)                                                                   \
  __builtin_amdgcn_global_load_lds((const __attribute__((address_space(1))) void*)(g),  \
                                   (__attribute__((address_space(3))) void*)(l), 16, 0, 0)

__device__ __forceinline__ unsigned lds_addr(const bf16* p) {
  return (unsigned)(uintptr_t)(const __attribute__((address_space(3))) bf16*)p;
}

// hardware transpose read: lane l receives column (l&15) (4 bf16, rows j=0..3) of the
// 4x16 subtile whose 16 lanes supply base + (l&15)*8 bytes. OFF walks k-subtiles.
template <int OFF>
__device__ __forceinline__ bf16x4 tr_read(unsigned addr) {
  bf16x4 r;
  if constexpr (OFF == 0)
    asm volatile("ds_read_b64_tr_b16 %0, %1" : "=v"(r) : "v"(addr));
  else if constexpr (OFF == 512)
    asm volatile("ds_read_b64_tr_b16 %0, %1 offset:512" : "=v"(r) : "v"(addr));
  else
    asm volatile("ds_read_b64_tr_b16 %0, %1 offset:1024" : "=v"(r) : "v"(addr));
  return r;
}

__device__ __forceinline__ bf16x8 cat8(bf16x4 a, bf16x4 b) {
  return __builtin_shufflevector(a, b, 0, 1, 2, 3, 4, 5, 6, 7);
}

// one convert task: 256 threads x 8 float4-units (8192 floats), 8 loads in flight
__device__ __forceinline__ void conv_task(const float* __restrict__ src,
                                          bf16* __restrict__ dst, int lt, int tid) {
  const size_t base = (size_t)lt * 2048 + tid;
  const float4* s4 = (const float4*)src;
  float4 f[8];
#pragma unroll
  for (int q = 0; q < 8; ++q) f[q] = s4[base + (size_t)q * 256];
  bf16x4* d4 = (bf16x4*)dst;
#pragma unroll
  for (int q = 0; q < 8; ++q) {
    bf16x4 p;
    p[0] = (bf16)f[q].x; p[1] = (bf16)f[q].y; p[2] = (bf16)f[q].z; p[3] = (bf16)f[q].w;
    d4[base + (size_t)q * 256] = p;
  }
}

// ================= prep: wgu/sgu/x convert + router_score + init =================
// task space: [0,2048) wgu; [2048,2176) sgu; [2176,2304) x.
// blocks [0,1152) grid-stride 2 tasks; [1152,1408) router_score; [1408,1412) init.
__global__ void prep_kernel(const float* __restrict__ x, bf16* __restrict__ xb,
                            const float* __restrict__ wgu, bf16* __restrict__ wguB,
                            const float* __restrict__ sgu, bf16* __restrict__ sguB,
                            const float* __restrict__ gw,
                            int* __restrict__ topk_e, float* __restrict__ topk_w,
                            int* __restrict__ counts, int* __restrict__ tok,
                            float* __restrict__ wt, int* __restrict__ slot) {
  const int b = blockIdx.x, tid = threadIdx.x;
  if (b < 1152) {
#pragma unroll
    for (int it = 0; it < 2; ++it) {
      const int task = b + it * 1152;
      if (task < 2048)      conv_task(wgu, wguB, task, tid);
      else if (task < 2176) conv_task(sgu, sguB, task - 2048, tid);
      else                  conv_task(x, xb, task - 2176, tid);
    }
  } else if (b < 1408) {     // ---- router_score
    const int wave = tid >> 6, lane = tid & 63;
    const int t = (b - 1152) * 4 + wave;
    const float4* xr = (const float4*)(x + (size_t)t * H_DIM);
    float4 xv[4];
#pragma unroll
    for (int j = 0; j < 4; ++j) xv[j] = xr[lane + 64 * j];
    float p[E_NUM];
#pragma unroll
    for (int e = 0; e < E_NUM; ++e) {
      const float4* gr = (const float4*)(gw + (size_t)e * H_DIM);
      float s = 0.f;
#pragma unroll
      for (int j = 0; j < 4; ++j) {
        float4 g = gr[lane + 64 * j];
        s += xv[j].x * g.x + xv[j].y * g.y + xv[j].z * g.z + xv[j].w * g.w;
      }
      p[e] = s;
    }
#pragma unroll
    for (int off = 32; off > 0; off >>= 1) {
#pragma unroll
      for (int e = 0; e < E_NUM; ++e) p[e] += __shfl_xor(p[e], off);
    }
    float rem[E_NUM];
#pragma unroll
    for (int e = 0; e < E_NUM; ++e) rem[e] = 1.f / (1.f + __expf(-p[e]));
    float vals[TOPK]; int idx[TOPK];
#pragma unroll
    for (int k = 0; k < TOPK; ++k) {
      float m = rem[0]; int mi = 0;
#pragma unroll
      for (int e = 1; e < E_NUM; ++e) {
        if (rem[e] > m) { m = rem[e]; mi = e; }
      }
      vals[k] = m; idx[k] = mi;
#pragma unroll
      for (int e = 0; e < E_NUM; ++e) rem[e] = (e == mi) ? -1e30f : rem[e];
    }
    if (lane == 0) {
      float inv = 1.f / (vals[0] + vals[1] + vals[2] + vals[3]);
      int4 ids; ids.x = idx[0]; ids.y = idx[1]; ids.z = idx[2]; ids.w = idx[3];
      float4 w4; w4.x = vals[0]*inv; w4.y = vals[1]*inv; w4.z = vals[2]*inv; w4.w = vals[3]*inv;
      ((int4*)topk_e)[t] = ids;
      ((float4*)topk_w)[t] = w4;
    }
  } else {                   // ---- init shared-expert list
    const int i = (b - 1408) * 256 + tid;
    if (i == 0) counts[E_NUM] = T_TOK;
    tok [E_NUM * T_TOK + i] = i;
    wt  [E_NUM * T_TOK + i] = 1.0f;
    slot[E_NUM * T_TOK + i] = T_TOK * TOPK + i;
  }
}

// ---------------- router phase 2: per-expert list build via ballot prefix ----------------
__global__ void router_build_kernel(const int* __restrict__ topk_e, const float* __restrict__ topk_w,
                                    int* __restrict__ counts, int* __restrict__ tok,
                                    float* __restrict__ wt, int* __restrict__ slot) {
  const int e = blockIdx.x;
  const int tid = threadIdx.x, wave = tid >> 6, lane = tid & 63;
  __shared__ int wsum[4];
  int base = 0;
  for (int r = 0; r < 4; ++r) {
    int t = r * 256 + tid;
    int4 ids = ((const int4*)topk_e)[t];
    int match = -1;
    if (ids.x == e) match = 0;
    if (ids.y == e) match = 1;
    if (ids.z == e) match = 2;
    if (ids.w == e) match = 3;
    unsigned long long bm = __ballot(match >= 0);
    int prefix = __popcll(bm & ((1ull << lane) - 1ull));
    if (lane == 0) wsum[wave] = __popcll(bm);
    __syncthreads();
    int wbase = 0;
#pragma unroll
    for (int wv = 0; wv < 4; ++wv) wbase += (wv < wave) ? wsum[wv] : 0;
    int total = wsum[0] + wsum[1] + wsum[2] + wsum[3];
    if (match >= 0) {
      int pos = base + wbase + prefix;
      tok [e * T_TOK + pos] = t;
      wt  [e * T_TOK + pos] = topk_w[t * 4 + match];
      slot[e * T_TOK + pos] = t * 4 + match;
    }
    base += total;
    __syncthreads();
  }
  if (tid == 0) counts[e] = base;
}

// ---------------- GEMM1 (z<17) + wd/sd convert blocks (z>=17) ----------------
// gemm1: Xb gathered @ Wgu(natural bf16) -> wt*swiglu -> h. Convert blocks stream
// wd/sd fp32->bf16 in gemm1's shadow; setprio(1) biases issue toward MFMA waves (T5).
__global__ __launch_bounds__(256, 4)
void gemm1_kernel(const bf16* __restrict__ xb, const bf16* __restrict__ wguB,
                  const bf16* __restrict__ sguB, const int* __restrict__ counts,
                  const int* __restrict__ tok, const float* __restrict__ wt,
                  const int* __restrict__ slot, bf16* __restrict__ hbuf,
                  const float* __restrict__ wdF, bf16* __restrict__ wdBo,
                  const float* __restrict__ sdF, bf16* __restrict__ sdBo) {
  const int tid = threadIdx.x;
  const int e = blockIdx.z;
  if (e >= 17) {  // ---- convert role: wd (1024 tasks) + sd (64 tasks)
    const int cid = (e - 17) * 128 + blockIdx.y * 8 + blockIdx.x;
    if (cid < 1024)      conv_task(wdF, wdBo, cid, tid);
    else if (cid < 1088) conv_task(sdF, sdBo, cid - 1024, tid);
    return;
  }
  const int cnt = counts[e];
  const int rt  = blockIdx.y;
  if (rt * 64 >= cnt) return;
  const int nb = blockIdx.x * 64;
  const bf16* WB = (e < E_NUM) ? (wguB + (size_t)e * H_DIM * (2 * I_DIM)) : sguB;

  __shared__ __align__(16) bf16 sA[3][64 * 32];
  __shared__ __align__(16) bf16 sG[3][2048];
  __shared__ __align__(16) bf16 sU[3][2048];

  const int wave = tid >> 6, lane = tid & 63;
  const int wr = wave >> 1, wc = wave & 1;
  const int fr = lane & 15, kg = lane >> 4;
  const int lr = lane >> 2, lk = (lane & 3) * 8;

  int ar = rt * 64 + wave * 16 + lr;
  int arc = ar < cnt ? ar : cnt - 1;
  const bf16* aS = xb + (size_t)tok[e * T_TOK + arc] * H_DIM + lk;
  const int aOff = wave * 512;

  const int k_off = 8 * wave + 4 * (lane >> 5) + ((lane & 7) >> 1);
  const int n_off = 16 * ((lane >> 3) & 3) + 8 * (lane & 1);
  const bf16* gS = WB + (size_t)k_off * (2 * I_DIM) + nb + n_off;
  const bf16* uS = WB + (size_t)k_off * (2 * I_DIM) + I_DIM + nb + n_off;
  const int wOff = wave * 512;

  f32x4 accg[2][2], accu[2][2];
#pragma unroll
  for (int i = 0; i < 2; ++i)
#pragma unroll
    for (int j = 0; j < 2; ++j) { accg[i][j] = f32x4{0,0,0,0}; accu[i][j] = f32x4{0,0,0,0}; }

#define STG1(t, bidx) do { size_t ko = (size_t)(t) * 32;    \
    GLOAD16(aS + ko, sA[bidx] + aOff);                      \
    GLOAD16(gS + ko * (2 * I_DIM), sG[bidx] + wOff);        \
    GLOAD16(uS + ko * (2 * I_DIM), sU[bidx] + wOff); } while (0)

  STG1(0, 0); STG1(1, 1);
  const int NT = H_DIM / 32;  // 32
  int bufc = 0;
  for (int t = 0; t < NT; ++t) {
    int bn = bufc + 2; bn = bn >= 3 ? bn - 3 : bn;
    if (t + 2 < NT) {
      STG1(t + 2, bn);
      asm volatile("s_waitcnt vmcnt(6)" ::: "memory");
    } else if (t + 1 < NT) {
      asm volatile("s_waitcnt vmcnt(3)" ::: "memory");
    } else {
      asm volatile("s_waitcnt vmcnt(0)" ::: "memory");
    }
    __builtin_amdgcn_s_barrier();
    __builtin_amdgcn_sched_barrier(0);
    const bf16* A = sA[bufc];
    bf16x8 a0 = *(const bf16x8*)(A + (wr * 32      + fr) * 32 + kg * 8);
    bf16x8 a1 = *(const bf16x8*)(A + (wr * 32 + 16 + fr) * 32 + kg * 8);
    unsigned gb = lds_addr(sG[bufc]) + (unsigned)((lane >> 4) << 10) + (unsigned)((lane & 15) << 3);
    unsigned ub = lds_addr(sU[bufc]) + (unsigned)((lane >> 4) << 10) + (unsigned)((lane & 15) << 3);
    unsigned nb0 = (unsigned)(wc * 256), nb1 = nb0 + 128;
    bf16x8 g0 = cat8(tr_read<0>(gb + nb0), tr_read<512>(gb + nb0));
    bf16x8 g1 = cat8(tr_read<0>(gb + nb1), tr_read<512>(gb + nb1));
    bf16x8 u0 = cat8(tr_read<0>(ub + nb0), tr_read<512>(ub + nb0));
    bf16x8 u1 = cat8(tr_read<0>(ub + nb1), tr_read<512>(ub + nb1));
    asm volatile("s_waitcnt lgkmcnt(0)" ::: "memory");
    __builtin_amdgcn_sched_barrier(0);
    __builtin_amdgcn_s_setprio(1);
    accg[0][0] = __builtin_amdgcn_mfma_f32_16x16x32_bf16(a0, g0, accg[0][0], 0, 0, 0);
    accg[0][1] = __builtin_amdgcn_mfma_f32_16x16x32_bf16(a0, g1, accg[0][1], 0, 0, 0);
    accg[1][0] = __builtin_amdgcn_mfma_f32_16x16x32_bf16(a1, g0, accg[1][0], 0, 0, 0);
    accg[1][1] = __builtin_amdgcn_mfma_f32_16x16x32_bf16(a1, g1, accg[1][1], 0, 0, 0);
    accu[0][0] = __builtin_amdgcn_mfma_f32_16x16x32_bf16(a0, u0, accu[0][0], 0, 0, 0);
    accu[0][1] = __builtin_amdgcn_mfma_f32_16x16x32_bf16(a0, u1, accu[0][1], 0, 0, 0);
    accu[1][0] = __builtin_amdgcn_mfma_f32_16x16x32_bf16(a1, u0, accu[1][0], 0, 0, 0);
    accu[1][1] = __builtin_amdgcn_mfma_f32_16x16x32_bf16(a1, u1, accu[1][1], 0, 0, 0);
    __builtin_amdgcn_s_setprio(0);
    __builtin_amdgcn_sched_barrier(0);
    __builtin_amdgcn_s_barrier();
    bufc = bufc == 2 ? 0 : bufc + 1;
  }
#undef STG1

#pragma unroll
  for (int mi = 0; mi < 2; ++mi) {
#pragma unroll
    for (int j = 0; j < 4; ++j) {
      int grow = rt * 64 + wr * 32 + mi * 16 + kg * 4 + j;
      if (grow < cnt) {
        bf16* hr = hbuf + (size_t)slot[e * T_TOK + grow] * I_DIM;
        float w = wt[e * T_TOK + grow];
#pragma unroll
        for (int ni = 0; ni < 2; ++ni) {
          float g = accg[mi][ni][j], u = accu[mi][ni][j];
          float h = w * (g / (1.f + __expf(-g))) * u;
          hr[nb + wc * 32 + ni * 16 + fr] = (bf16)h;
        }
      }
    }
  }
}

// ---------------- GEMM2: h gathered @ Wd(natural bf16) -> bf16 stores into obuf ----------------
__global__ __launch_bounds__(256, 4)
void gemm2_kernel(const bf16* __restrict__ hbuf, const bf16* __restrict__ wdB,
                  const bf16* __restrict__ sdB, const int* __restrict__ counts,
                  const int* __restrict__ slot, bf16* __restrict__ obuf) {
  const int e   = blockIdx.z;
  const int cnt = counts[e];
  const int rt  = blockIdx.y;
  if (rt * 64 >= cnt) return;
  const int nb = blockIdx.x * 128;
  const bf16* WB = (e < E_NUM) ? (wdB + (size_t)e * I_DIM * H_DIM) : sdB;

  __shared__ __align__(16) bf16 sA[3][64 * 32];
  __shared__ __align__(16) bf16 sB[3][4096];

  const int tid = threadIdx.x, wave = tid >> 6, lane = tid & 63;
  const int wr = wave >> 1, wc = wave & 1;
  const int fr = lane & 15, kg = lane >> 4;
  const int lr = lane >> 2, lk = (lane & 3) * 8;

  int ar = rt * 64 + wave * 16 + lr;
  int arc = ar < cnt ? ar : cnt - 1;
  const bf16* aS = hbuf + (size_t)slot[e * T_TOK + arc] * I_DIM + lk;
  const int aOff = wave * 512;

  const int j2 = (lane & 7) >> 1, h2 = lane & 1, nblk2 = lane >> 3;
  const int n2 = nb + nblk2 * 16 + 8 * h2;
  const bf16* bS0 = WB + (size_t)((wave * 2 + 0) * 4 + j2) * H_DIM + n2;
  const bf16* bS1 = WB + (size_t)((wave * 2 + 1) * 4 + j2) * H_DIM + n2;
  const int bOff0 = wave * 1024;
  const int bOff1 = bOff0 + 512;

  f32x4 acc[2][4];
#pragma unroll
  for (int i = 0; i < 2; ++i)
#pragma unroll
    for (int j = 0; j < 4; ++j) acc[i][j] = f32x4{0,0,0,0};

#define STG2(t, bidx) do { size_t ko = (size_t)(t) * 32;    \
    GLOAD16(aS + ko, sA[bidx] + aOff);                      \
    GLOAD16(bS0 + ko * H_DIM, sB[bidx] + bOff0);            \
    GLOAD16(bS1 + ko * H_DIM, sB[bidx] + bOff1); } while (0)

  STG2(0, 0); STG2(1, 1);
  const int NT = I_DIM / 32;  // 16
  int bufc = 0;
  for (int t = 0; t < NT; ++t) {
    int bn = bufc + 2; bn = bn >= 3 ? bn - 3 : bn;
    if (t + 2 < NT) {
      STG2(t + 2, bn);
      asm volatile("s_waitcnt vmcnt(6)" ::: "memory");
    } else if (t + 1 < NT) {
      asm volatile("s_waitcnt vmcnt(3)" ::: "memory");
    } else {
      asm volatile("s_waitcnt vmcnt(0)" ::: "memory");
    }
    __builtin_amdgcn_s_barrier();
    __builtin_amdgcn_sched_barrier(0);
    const bf16* A = sA[bufc];
    bf16x8 a0 = *(const bf16x8*)(A + (wr * 32      + fr) * 32 + kg * 8);
    bf16x8 a1 = *(const bf16x8*)(A + (wr * 32 + 16 + fr) * 32 + kg * 8);
    unsigned bb = lds_addr(sB[bufc]) + (unsigned)((lane >> 4) << 11) + (unsigned)((lane & 15) << 3)
                + (unsigned)(wc * 512);
    bf16x8 b[4];
#pragma unroll
    for (int ni = 0; ni < 4; ++ni)
      b[ni] = cat8(tr_read<0>(bb + ni * 128), tr_read<1024>(bb + ni * 128));
    asm volatile("s_waitcnt lgkmcnt(0)" ::: "memory");
    __builtin_amdgcn_sched_barrier(0);
#pragma unroll
    for (int ni = 0; ni < 4; ++ni) {
      acc[0][ni] = __builtin_amdgcn_mfma_f32_16x16x32_bf16(a0, b[ni], acc[0][ni], 0, 0, 0);
      acc[1][ni] = __builtin_amdgcn_mfma_f32_16x16x32_bf16(a1, b[ni], acc[1][ni], 0, 0, 0);
    }
    __builtin_amdgcn_sched_barrier(0);
    __builtin_amdgcn_s_barrier();
    bufc = bufc == 2 ? 0 : bufc + 1;
  }
#undef STG2

#pragma unroll
  for (int mi = 0; mi < 2; ++mi) {
#pragma unroll
    for (int j = 0; j < 4; ++j) {
      int grow = rt * 64 + wr * 32 + mi * 16 + kg * 4 + j;
      if (grow < cnt) {
        bf16* orow = obuf + (size_t)slot[e * T_TOK + grow] * H_DIM + nb + wc * 64 + fr;
#pragma unroll
        for (int ni = 0; ni < 4; ++ni)
          orow[ni * 16] = (bf16)acc[mi][ni][j];
      }
    }
  }
}

// ---------------- reduce: out[t] = sum_k obuf[t*4+k] + obuf[4096+t] (bf16 -> fp32) ----------------
__global__ void reduce_kernel(const bf16* __restrict__ obuf, float* __restrict__ out) {
  const int t = blockIdx.x;
  const int c = threadIdx.x;   // 256 chunks of 4 elems per row
  const bf16x4* o4 = (const bf16x4*)obuf;
  float4 s; s.x = s.y = s.z = s.w = 0.f;
  int rows[5] = {t * 4, t * 4 + 1, t * 4 + 2, t * 4 + 3, T_TOK * TOPK + t};
#pragma unroll
  for (int r = 0; r < 5; ++r) {
    bf16x4 v = o4[(size_t)rows[r] * 256 + c];
    s.x += (float)v[0]; s.y += (float)v[1]; s.z += (float)v[2]; s.w += (float)v[3];
  }
  ((float4*)out)[(size_t)t * 256 + c] = s;
}

extern "C" void kernel_launch(void* const* d_in, const int* in_sizes, int n_in,
                              void* d_out, int out_size, void* d_ws, size_t ws_size,
                              hipStream_t stream) {
  const float* x   = (const float*)d_in[0];
  const float* gw  = (const float*)d_in[1];
  const float* wgu = (const float*)d_in[2];
  const float* wd  = (const float*)d_in[3];
  const float* sgu = (const float*)d_in[4];
  const float* sd  = (const float*)d_in[5];
  float* out = (float*)d_out;

  char* ws = (char*)d_ws;
  int*   counts = (int*)  (ws);                 // 1 KB
  int*   tok    = (int*)  (ws + 1024);          // 68 KB
  float* wtA    = (float*)(ws + 70656);         // 68 KB
  int*   slotA  = (int*)  (ws + 140288);        // 68 KB
  int*   topk_e = (int*)  (ws + 209920);        // 16 KB
  float* topk_w = (float*)(ws + 226304);        // 16 KB
  bf16*  xb     = (bf16*) (ws + 245760);        // 2 MB
  bf16*  hbuf   = (bf16*) (ws + 2342912);       // 5.25 MB
  bf16*  wguB   = (bf16*) (ws + 7585792);       // 32 MB  natural [E][1024][1024]
  bf16*  wdB    = (bf16*) (ws + 41140224);      // 16 MB  natural [E][512][1024]
  bf16*  sguB   = (bf16*) (ws + 57917440);      // 2 MB
  bf16*  sdB    = (bf16*) (ws + 60014592);      // 1 MB
  // obuf (10 MB bf16 [5120][1024]) aliases wguB: dead after gemm1, rewritten by
  // prep before gemm1 on every call.
  bf16*  obuf   = (bf16*) (ws + 7585792);

  prep_kernel<<<1412, 256, 0, stream>>>(x, xb, wgu, wguB, sgu, sguB,
                                        gw, topk_e, topk_w, counts, tok, wtA, slotA);
  router_build_kernel<<<E_NUM, 256, 0, stream>>>(topk_e, topk_w, counts, tok, wtA, slotA);
  gemm1_kernel<<<dim3(8, 16, 26), 256, 0, stream>>>(xb, wguB, sguB, counts, tok, wtA, slotA,
                                                    hbuf, wd, wdB, sd, sdB);
  gemm2_kernel<<<dim3(8, 16, 17), 256, 0, stream>>>(hbuf, wdB, sdB, counts, slotA, obuf);
  reduce_kernel<<<T_TOK, 256, 0, stream>>>(obuf, out);
}